// Round 1
// baseline (2592.132 us; speedup 1.0000x reference)
//
#include <hip/hip_runtime.h>
#include <hip/hip_bf16.h>
#include <math.h>

#define Bdim 8
#define Tdim 1024
#define Cdim 768
#define Hdim 24
#define Ndim 32
#define BTdim (Bdim*Tdim)

__device__ __forceinline__ float sigm(float x){ return 1.f/(1.f+expf(-x)); }
__device__ __forceinline__ float softplusf(float x){ return fmaxf(x,0.f) + log1pf(expf(-fabsf(x))); }

// ---------------- K1: token shift: xx = x[t-1]-x[t], xxx = x + xx*maa_x ----------------
__global__ void k1_shift(const float* __restrict__ x, const float* __restrict__ maa_x,
                         float* __restrict__ xx, float* __restrict__ xxx) {
  int idx = blockIdx.x*256 + threadIdx.x;
  if (idx >= BTdim*Cdim) return;
  int c = idx % Cdim; int row = idx / Cdim; int t = row % Tdim;
  float xv = x[idx];
  float xp = (t==0) ? 0.f : x[idx - Cdim];
  float d = xp - xv;
  xx[idx] = d;
  xxx[idx] = xv + d*maa_x[c];
}

// ---------------- generic f32 GEMM: O = act(A[M,K] @ W[K,N]) ----------------
// 64x64 tile, BLK_K=16, 256 threads, each thread 4x4 outputs.
template<int ACT>
__global__ __launch_bounds__(256) void gemm_f32(const float* __restrict__ A,
    const float* __restrict__ W, float* __restrict__ O, int M, int K, int N) {
  __shared__ float As[16][68];
  __shared__ float Ws[16][68];
  const int bm = blockIdx.y*64, bn = blockIdx.x*64;
  const int tid = threadIdx.x;
  const int tm0 = (tid>>4)<<2, tn0 = (tid&15)<<2;
  float acc[4][4] = {};
  for (int k0=0; k0<K; k0+=16) {
    #pragma unroll
    for (int i=0;i<4;i++){
      int l = tid + i*256;
      int m = l>>4, kk = l&15;
      As[kk][m] = A[(size_t)(bm+m)*K + k0+kk];
    }
    #pragma unroll
    for (int i=0;i<4;i++){
      int l = tid + i*256;
      int kk = l>>6, n = l&63;
      Ws[kk][n] = (bn+n < N) ? W[(size_t)(k0+kk)*N + bn+n] : 0.f;
    }
    __syncthreads();
    #pragma unroll
    for (int kk=0;kk<16;kk++){
      float4 a4 = *(const float4*)&As[kk][tm0];
      float4 b4 = *(const float4*)&Ws[kk][tn0];
      float av[4]={a4.x,a4.y,a4.z,a4.w}, bv[4]={b4.x,b4.y,b4.z,b4.w};
      #pragma unroll
      for (int i=0;i<4;i++)
        #pragma unroll
        for (int j=0;j<4;j++)
          acc[i][j] += av[i]*bv[j];
    }
    __syncthreads();
  }
  #pragma unroll
  for (int i=0;i<4;i++){
    int m = bm+tm0+i;
    #pragma unroll
    for (int j=0;j<4;j++){
      int n = bn+tn0+j;
      if (n < N) {
        float v = acc[i][j];
        if (ACT==1) v = tanhf(v);
        else if (ACT==2) v = sigm(v);
        O[(size_t)m*N + n] = v;
      }
    }
  }
}

// ---------------- K2b: mix = einsum(tm, maa_w2); xrg/xwa/xk/xv ----------------
__global__ __launch_bounds__(256) void k2_mix(const float* __restrict__ x, const float* __restrict__ xx,
    const float* __restrict__ tm, const float* __restrict__ w2,
    const float* __restrict__ mrg, const float* __restrict__ mwa,
    const float* __restrict__ mk_, const float* __restrict__ mv_,
    float* __restrict__ xrg, float* __restrict__ xwa, float* __restrict__ xk, float* __restrict__ xv) {
  const int row = blockIdx.x, tid = threadIdx.x;
  __shared__ float stm[112];
  if (tid<112) stm[tid]=tm[(size_t)row*112+tid];
  __syncthreads();
  for (int c=tid;c<Cdim;c+=256){
    float m0=0.f,m1=0.f,m2=0.f,m3=0.f;
    #pragma unroll 7
    for (int d=0; d<28; d++){
      m0 += stm[d]    * w2[(size_t)(d)*Cdim + c];
      m1 += stm[28+d] * w2[(size_t)(28+d)*Cdim + c];
      m2 += stm[56+d] * w2[(size_t)(56+d)*Cdim + c];
      m3 += stm[84+d] * w2[(size_t)(84+d)*Cdim + c];
    }
    size_t i=(size_t)row*Cdim+c;
    float xval=x[i], d_=xx[i];
    xrg[i]=xval + d_*(mrg[c]+m0);
    xwa[i]=xval + d_*(mwa[c]+m1);
    xk[i] =xval + d_*(mk_[c]+m2);
    xv[i] =xval + d_*(mv_[c]+m3);
  }
}

// ---------------- K5: fused second-stage small gemms + elementwise + kk-normalize ----------------
__global__ __launch_bounds__(256) void k5_fuse(
    const float* __restrict__ h1, const float* __restrict__ h2, const float* __restrict__ h3,
    const float* __restrict__ h4, const float* __restrict__ h5, const float* __restrict__ h6,
    const float* __restrict__ h7,
    const float* __restrict__ dw2, const float* __restrict__ aaa_w2, const float* __restrict__ kkk_w2,
    const float* __restrict__ gate_w2, const float* __restrict__ ma_w2, const float* __restrict__ mk_w2,
    const float* __restrict__ mv_w2,
    const float* __restrict__ time_decay, const float* __restrict__ time_aaaaa,
    const float* __restrict__ misc_a, const float* __restrict__ misc_k, const float* __restrict__ misc_v,
    const float* __restrict__ v1,
    float* __restrict__ kbuf, float* __restrict__ vbuf, float* __restrict__ wexp,
    float* __restrict__ g, float* __restrict__ akv, float* __restrict__ bkv) {
  const int row = blockIdx.x, tid = threadIdx.x;
  __shared__ float s1[64], s2[24], s3[24], s4[120], s5[24], s6[24], s7[24];
  __shared__ float kkp[Cdim], aarr[Cdim];
  __shared__ float hinv[Hdim];
  if (tid<64)  s1[tid]=h1[(size_t)row*64+tid];
  if (tid<24){ s2[tid]=h2[(size_t)row*24+tid]; s3[tid]=h3[(size_t)row*24+tid];
               s5[tid]=h5[(size_t)row*24+tid]; s6[tid]=h6[(size_t)row*24+tid];
               s7[tid]=h7[(size_t)row*24+tid]; }
  if (tid>=128 && tid<248) s4[tid-128]=h4[(size_t)row*120+(tid-128)];
  __syncthreads();
  for (int c=tid;c<Cdim;c+=256){
    size_t i = (size_t)row*Cdim + c;
    float zd = time_decay[c];
    #pragma unroll 8
    for (int q=0;q<64;q++) zd += s1[q]*dw2[q*Cdim+c];
    float w = -softplusf(-zd) - 0.5f;
    wexp[i] = expf(-expf(w));
    float za = time_aaaaa[c];
    float zkk = 0.f, zg=0.f, zma=misc_a[c], zmk=misc_k[c], zmv=misc_v[c];
    #pragma unroll 8
    for (int q=0;q<24;q++){
      za  += s2[q]*aaa_w2[q*Cdim+c];
      zkk += s3[q]*kkk_w2[q*Cdim+c];
      zma += s5[q]*ma_w2[q*Cdim+c];
      zmk += s6[q]*mk_w2[q*Cdim+c];
      zmv += s7[q]*mv_w2[q*Cdim+c];
    }
    #pragma unroll 8
    for (int q=0;q<120;q++) zg += s4[q]*gate_w2[q*Cdim+c];
    float a = sigm(za);
    float kraw = kbuf[i];
    kkp[c] = kraw + zkk;       // kk pre-normalize
    aarr[c] = a;
    g[i] = zg;
    float ma = sigm(zma), mk = sigm(zmk), mv = sigm(zmv);
    float v0 = vbuf[i];
    vbuf[i] = v0 + (v1[i]-v0)*mv;
    float k1 = kraw*(ma + a*(1.f-ma));
    kbuf[i] = k1 * expf(fminf(w*mk, 0.f));
  }
  __syncthreads();
  if (tid < Hdim){
    float s=0.f;
    #pragma unroll
    for (int j=0;j<Ndim;j++){ float q=kkp[tid*Ndim+j]; s += q*q; }
    hinv[tid] = 1.f / fmaxf(sqrtf(s), 1e-12f);
  }
  __syncthreads();
  for (int c=tid;c<Cdim;c+=256){
    size_t i = (size_t)row*Cdim + c;
    float kkn = kkp[c]*hinv[c>>5];
    akv[i] = -kkn;
    bkv[i] = kkn*aarr[c];
  }
}

// ---------------- K6: WKV7 recurrence. One block (32 threads) per (b,h). ----------------
// Thread i owns state row S[i][0..31]. Broadcast of r,w,k,a,b via LDS; v kept per-thread.
__global__ __launch_bounds__(32) void k6_wkv(const float* __restrict__ r, const float* __restrict__ wexp,
    const float* __restrict__ k, const float* __restrict__ v,
    const float* __restrict__ a, const float* __restrict__ b2, float* __restrict__ y) {
  const int head = blockIdx.x;
  const int bb = head / Hdim, hh = head - bb*Hdim;
  const int i = threadIdx.x;
  __shared__ __align__(16) float sr[Ndim], sw[Ndim], sk[Ndim], sa[Ndim], sb[Ndim];
  float S[Ndim];
  #pragma unroll
  for (int j=0;j<Ndim;j++) S[j]=0.f;
  size_t base = ((size_t)bb*Tdim)*Cdim + (size_t)hh*Ndim + i;
  float rt=r[base], wt=wexp[base], kt=k[base], vt=v[base], at=a[base], bt=b2[base];
  for (int t=0;t<Tdim;t++){
    sr[i]=rt; sw[i]=wt; sk[i]=kt; sa[i]=at; sb[i]=bt;
    const float vloc = vt;
    __syncthreads();
    if (t+1<Tdim){                    // prefetch next step's operands (latency hides under compute)
      size_t nb = base + Cdim;
      rt=r[nb]; wt=wexp[nb]; kt=k[nb]; vt=v[nb]; at=a[nb]; bt=b2[nb];
    }
    float sav=0.f;
    #pragma unroll
    for (int j=0;j<Ndim;j++) sav += S[j]*sa[j];
    float yv=0.f;
    #pragma unroll
    for (int j=0;j<Ndim;j++){
      float s = S[j]*sw[j] + sav*sb[j] + vloc*sk[j];
      S[j]=s;
      yv += s*sr[j];
    }
    y[base]=yv;
    base += Cdim;
    __syncthreads();
  }
}

// ---------------- K7: GroupNorm + bonus + gate ----------------
__global__ __launch_bounds__(256) void k7_post(const float* __restrict__ y,
    const float* __restrict__ r, const float* __restrict__ kf, const float* __restrict__ v,
    const float* __restrict__ g, const float* __restrict__ faaaa,
    const float* __restrict__ lnw, const float* __restrict__ lnb,
    float* __restrict__ ygate) {
  const int row = blockIdx.x, tid = threadIdx.x;
  __shared__ float sy[Cdim], srk[Cdim];
  __shared__ float smu[Hdim], srs[Hdim], sbon[Hdim];
  for (int c=tid;c<Cdim;c+=256){
    size_t i=(size_t)row*Cdim+c;
    float yv=y[i]; sy[c]=yv;
    srk[c]=r[i]*kf[i]*faaaa[c];
  }
  __syncthreads();
  if (tid<Hdim){
    float s=0.f,ss=0.f,bn=0.f;
    #pragma unroll
    for (int j=0;j<Ndim;j++){
      float q=sy[tid*Ndim+j]; s+=q; ss+=q*q; bn+=srk[tid*Ndim+j];
    }
    float mu=s*(1.f/Ndim);
    float var=ss*(1.f/Ndim)-mu*mu;
    smu[tid]=mu; srs[tid]=rsqrtf(var+6.4e-5f); sbon[tid]=bn;
  }
  __syncthreads();
  for (int c=tid;c<Cdim;c+=256){
    size_t i=(size_t)row*Cdim+c; int h=c>>5;
    float yn=(sy[c]-smu[h])*srs[h]*lnw[c]+lnb[c];
    ygate[i]=(yn+sbon[h]*v[i])*g[i];
  }
}

// ---------------- K9: v1 passthrough ----------------
__global__ void k9_copy(const float* __restrict__ src, float* __restrict__ dst){
  int idx = blockIdx.x*256 + threadIdx.x;
  if (idx < BTdim*Cdim) dst[idx]=src[idx];
}

extern "C" void kernel_launch(void* const* d_in, const int* in_sizes, int n_in,
                              void* d_out, int out_size, void* d_ws, size_t ws_size,
                              hipStream_t stream) {
  const float* x      = (const float*)d_in[0];
  const float* v1     = (const float*)d_in[1];
  const float* maa_x  = (const float*)d_in[2];
  const float* maa_rg = (const float*)d_in[3];
  const float* maa_wa = (const float*)d_in[4];
  const float* maa_k  = (const float*)d_in[5];
  const float* maa_v  = (const float*)d_in[6];
  const float* time_decay = (const float*)d_in[7];
  const float* faaaa  = (const float*)d_in[8];
  const float* aaaaa  = (const float*)d_in[9];
  const float* maa_w1 = (const float*)d_in[10];
  const float* maa_w2 = (const float*)d_in[11];
  const float* dw1    = (const float*)d_in[12];
  const float* dw2    = (const float*)d_in[13];
  const float* aaa_w1 = (const float*)d_in[14];
  const float* aaa_w2 = (const float*)d_in[15];
  const float* kkk_w1 = (const float*)d_in[16];
  const float* kkk_w2 = (const float*)d_in[17];
  const float* gate_w1= (const float*)d_in[18];
  const float* gate_w2= (const float*)d_in[19];
  const float* ma_w1  = (const float*)d_in[20];
  const float* ma_w2  = (const float*)d_in[21];
  const float* misc_a = (const float*)d_in[22];
  const float* mk_w1  = (const float*)d_in[23];
  const float* mk_w2  = (const float*)d_in[24];
  const float* misc_k = (const float*)d_in[25];
  const float* mv_w1  = (const float*)d_in[26];
  const float* mv_w2  = (const float*)d_in[27];
  const float* misc_v = (const float*)d_in[28];
  const float* Wr     = (const float*)d_in[29];
  const float* Wk     = (const float*)d_in[30];
  const float* Wv     = (const float*)d_in[31];
  const float* Wo     = (const float*)d_in[32];
  const float* lnw    = (const float*)d_in[33];
  const float* lnb    = (const float*)d_in[34];
  float* out = (float*)d_out;

  float* ws = (float*)d_ws;
  const size_t BTC = (size_t)BTdim*Cdim;
  float* xx  = ws + 0*BTC;
  float* xxx = ws + 1*BTC;
  float* xrg = ws + 2*BTC;
  float* xwa = ws + 3*BTC;
  float* xk  = ws + 4*BTC;
  float* xv  = ws + 5*BTC;
  float* rb  = ws + 6*BTC;
  float* kb  = ws + 7*BTC;
  float* vb  = ws + 8*BTC;
  float* tm  = ws + 9*BTC;                 // BTdim*112
  float* h1  = tm + (size_t)BTdim*112;     // *64
  float* h2  = h1 + (size_t)BTdim*64;      // *24
  float* h3  = h2 + (size_t)BTdim*24;
  float* h4  = h3 + (size_t)BTdim*24;      // *120
  float* h5  = h4 + (size_t)BTdim*120;
  float* h6  = h5 + (size_t)BTdim*24;
  float* h7  = h6 + (size_t)BTdim*24;
  // aliases (producer of the original buffer is fully consumed before these are written)
  float* ybuf  = xx;
  float* ygate = xxx;
  float* akv   = xrg;
  float* bkv   = xwa;
  float* gb    = xk;
  float* wexp  = xv;

  dim3 blk(256);
  k1_shift<<<dim3((BTdim*Cdim+255)/256), blk, 0, stream>>>(x, maa_x, xx, xxx);
  gemm_f32<1><<<dim3(2,128),  blk, 0, stream>>>(xxx, maa_w1, tm, BTdim, Cdim, 112);
  k2_mix<<<dim3(BTdim), blk, 0, stream>>>(x, xx, tm, maa_w2, maa_rg, maa_wa, maa_k, maa_v,
                                          xrg, xwa, xk, xv);
  gemm_f32<0><<<dim3(12,128), blk, 0, stream>>>(xrg, Wr, rb, BTdim, Cdim, Cdim);
  gemm_f32<0><<<dim3(12,128), blk, 0, stream>>>(xk,  Wk, kb, BTdim, Cdim, Cdim);
  gemm_f32<0><<<dim3(12,128), blk, 0, stream>>>(xv,  Wv, vb, BTdim, Cdim, Cdim);
  gemm_f32<1><<<dim3(1,128),  blk, 0, stream>>>(xwa, dw1,    h1, BTdim, Cdim, 64);
  gemm_f32<0><<<dim3(1,128),  blk, 0, stream>>>(xwa, aaa_w1, h2, BTdim, Cdim, 24);
  gemm_f32<1><<<dim3(1,128),  blk, 0, stream>>>(xk,  kkk_w1, h3, BTdim, Cdim, 24);
  gemm_f32<2><<<dim3(2,128),  blk, 0, stream>>>(xrg, gate_w1,h4, BTdim, Cdim, 120);
  gemm_f32<0><<<dim3(1,128),  blk, 0, stream>>>(xwa, ma_w1,  h5, BTdim, Cdim, 24);
  gemm_f32<0><<<dim3(1,128),  blk, 0, stream>>>(xk,  mk_w1,  h6, BTdim, Cdim, 24);
  gemm_f32<0><<<dim3(1,128),  blk, 0, stream>>>(xv,  mv_w1,  h7, BTdim, Cdim, 24);
  k5_fuse<<<dim3(BTdim), blk, 0, stream>>>(h1,h2,h3,h4,h5,h6,h7,
      dw2,aaa_w2,kkk_w2,gate_w2,ma_w2,mk_w2,mv_w2,
      time_decay, aaaaa, misc_a, misc_k, misc_v, v1,
      kb, vb, wexp, gb, akv, bkv);
  k6_wkv<<<dim3(Bdim*Hdim), dim3(32), 0, stream>>>(rb, wexp, kb, vb, akv, bkv, ybuf);
  k7_post<<<dim3(BTdim), blk, 0, stream>>>(ybuf, rb, kb, vb, gb, faaaa, lnw, lnb, ygate);
  gemm_f32<0><<<dim3(12,128), blk, 0, stream>>>(ygate, Wo, out, BTdim, Cdim, Cdim);
  k9_copy<<<dim3((BTdim*Cdim+255)/256), blk, 0, stream>>>(v1, out + BTC);
}

// Round 2
// 2115.459 us; speedup vs baseline: 1.2253x; 1.2253x over previous
//
#include <hip/hip_runtime.h>
#include <hip/hip_bf16.h>
#include <math.h>

#define Bdim 8
#define Tdim 1024
#define Cdim 768
#define Hdim 24
#define Ndim 32
#define BTdim (Bdim*Tdim)
#define CH 8

typedef __attribute__((ext_vector_type(8))) short bf16x8;
typedef __attribute__((ext_vector_type(4))) float f32x4;

__device__ __forceinline__ float sigm(float x){ return 1.f/(1.f+expf(-x)); }
__device__ __forceinline__ float softplusf(float x){ return fmaxf(x,0.f) + log1pf(expf(-fabsf(x))); }

#define GLDS(gp, lp) __builtin_amdgcn_global_load_lds((const __attribute__((address_space(1))) void*)(gp), (__attribute__((address_space(3))) void*)(lp), 16, 0, 0)

// ---------------- K1: token shift ----------------
__global__ void k1_shift(const float* __restrict__ x, const float* __restrict__ maa_x,
                         float* __restrict__ xx, float* __restrict__ xxx) {
  int idx = blockIdx.x*256 + threadIdx.x;
  if (idx >= BTdim*Cdim) return;
  int c = idx % Cdim; int row = idx / Cdim; int t = row % Tdim;
  float xv = x[idx];
  float xp = (t==0) ? 0.f : x[idx - Cdim];
  float d = xp - xv;
  xx[idx] = d;
  xxx[idx] = xv + d*maa_x[c];
}

// ---------------- weight convert + transpose: Wt[n][k] = bf16(W[k][n]) ----------------
__global__ __launch_bounds__(256) void kconvW(const float* __restrict__ W0, const float* __restrict__ W1,
    const float* __restrict__ W2, const float* __restrict__ W3,
    __hip_bfloat16* __restrict__ T0, __hip_bfloat16* __restrict__ T1,
    __hip_bfloat16* __restrict__ T2, __hip_bfloat16* __restrict__ T3) {
  const float* Wsrc[4] = {W0,W1,W2,W3};
  __hip_bfloat16* Tdst[4] = {T0,T1,T2,T3};
  const float* W = Wsrc[blockIdx.z];
  __hip_bfloat16* T = Tdst[blockIdx.z];
  __shared__ float tile[32][33];
  int bx = blockIdx.x*32, by = blockIdx.y*32;  // bx: n-block, by: k-block
  int tx = threadIdx.x & 31, ty = threadIdx.x >> 5;  // 32 x 8
  #pragma unroll
  for (int q=0;q<32;q+=8) tile[ty+q][tx] = W[(size_t)(by+ty+q)*Cdim + bx+tx];
  __syncthreads();
  #pragma unroll
  for (int q=0;q<32;q+=8) T[(size_t)(bx+ty+q)*Cdim + by+tx] = __float2bfloat16(tile[tx][ty+q]);
}

// ---------------- generic small GEMM: O = act(A[M,K] @ W[K,N]), A f32 or bf16 ----------------
template<int ACT, typename TA>
__global__ __launch_bounds__(256) void gemm_f32(const TA* __restrict__ A,
    const float* __restrict__ W, float* __restrict__ O, int M, int K, int N) {
  __shared__ float As[16][68];
  __shared__ float Ws[16][68];
  const int bm = blockIdx.y*64, bn = blockIdx.x*64;
  const int tid = threadIdx.x;
  const int tm0 = (tid>>4)<<2, tn0 = (tid&15)<<2;
  float acc[4][4] = {};
  for (int k0=0; k0<K; k0+=16) {
    #pragma unroll
    for (int i=0;i<4;i++){
      int l = tid + i*256;
      int m = l>>4, kk = l&15;
      As[kk][m] = (float)A[(size_t)(bm+m)*K + k0+kk];
    }
    #pragma unroll
    for (int i=0;i<4;i++){
      int l = tid + i*256;
      int kk = l>>6, n = l&63;
      Ws[kk][n] = (bn+n < N) ? W[(size_t)(k0+kk)*N + bn+n] : 0.f;
    }
    __syncthreads();
    #pragma unroll
    for (int kk=0;kk<16;kk++){
      float4 a4 = *(const float4*)&As[kk][tm0];
      float4 b4 = *(const float4*)&Ws[kk][tn0];
      float av[4]={a4.x,a4.y,a4.z,a4.w}, bv[4]={b4.x,b4.y,b4.z,b4.w};
      #pragma unroll
      for (int i=0;i<4;i++)
        #pragma unroll
        for (int j=0;j<4;j++)
          acc[i][j] += av[i]*bv[j];
    }
    __syncthreads();
  }
  #pragma unroll
  for (int i=0;i<4;i++){
    int m = bm+tm0+i;
    #pragma unroll
    for (int j=0;j<4;j++){
      int n = bn+tn0+j;
      if (n < N) {
        float v = acc[i][j];
        if (ACT==1) v = tanhf(v);
        else if (ACT==2) v = sigm(v);
        O[(size_t)m*N + n] = v;
      }
    }
  }
}

// ---------------- bf16 MFMA GEMM: C[M,N] f32 = A[M,K]bf16 @ Bt[N,K]bf16^T ----------------
// 128x128 tile, BK=32, 256 threads (4 waves, 2x2), global_load_lds staging (m97 structure).
__global__ __launch_bounds__(256) void gemm_mfma(const __hip_bfloat16* __restrict__ A,
    const __hip_bfloat16* __restrict__ Bt, float* __restrict__ C, int M, int N, int K) {
  __shared__ unsigned short As[128*32];
  __shared__ unsigned short Bs[128*32];
  const int bm = blockIdx.y*128, bn = blockIdx.x*128;
  const int tid = threadIdx.x, lane = tid&63, w = tid>>6;
  const int wr = w>>1, wc = w&1;
  const int lr = lane&15, kg = lane>>4;
  f32x4 zero = {0.f,0.f,0.f,0.f};
  f32x4 acc[4][4];
  #pragma unroll
  for (int m=0;m<4;m++)
    #pragma unroll
    for (int n=0;n<4;n++) acc[m][n]=zero;
  const size_t rowA = (size_t)(bm + w*32 + (lane>>2))*K + (lane&3)*8;
  const size_t rowB = (size_t)(bn + w*32 + (lane>>2))*K + (lane&3)*8;
  unsigned short* lA = As + w*32*32;
  unsigned short* lB = Bs + w*32*32;
  for (int k0=0; k0<K; k0+=32){
    GLDS(A + rowA + k0,                 lA);
    GLDS(A + rowA + k0 + (size_t)16*K,  lA + 512);
    GLDS(Bt + rowB + k0,                lB);
    GLDS(Bt + rowB + k0 + (size_t)16*K, lB + 512);
    __syncthreads();
    bf16x8 af[4], bfr[4];
    #pragma unroll
    for (int m=0;m<4;m++) af[m]  = *(const bf16x8*)(void*)(As + (wr*64+m*16+lr)*32 + kg*8);
    #pragma unroll
    for (int n=0;n<4;n++) bfr[n] = *(const bf16x8*)(void*)(Bs + (wc*64+n*16+lr)*32 + kg*8);
    #pragma unroll
    for (int m=0;m<4;m++)
      #pragma unroll
      for (int n=0;n<4;n++)
        acc[m][n] = __builtin_amdgcn_mfma_f32_16x16x32_bf16(af[m], bfr[n], acc[m][n], 0,0,0);
    __syncthreads();
  }
  #pragma unroll
  for (int m=0;m<4;m++)
    #pragma unroll
    for (int n=0;n<4;n++){
      size_t r0 = (size_t)(bm + wr*64 + m*16 + kg*4);
      int cc = bn + wc*64 + n*16 + lr;
      #pragma unroll
      for (int q=0;q<4;q++)
        C[(r0+q)*N + cc] = acc[m][n][q];
    }
}

// ---------------- K2b: mix + write 4 bf16 activation buffers ----------------
__global__ __launch_bounds__(256) void k2_mix(const float* __restrict__ x, const float* __restrict__ xx,
    const float* __restrict__ tm, const float* __restrict__ w2,
    const float* __restrict__ mrg, const float* __restrict__ mwa,
    const float* __restrict__ mk_, const float* __restrict__ mv_,
    __hip_bfloat16* __restrict__ xrg, __hip_bfloat16* __restrict__ xwa,
    __hip_bfloat16* __restrict__ xk, __hip_bfloat16* __restrict__ xv) {
  const int row = blockIdx.x, tid = threadIdx.x;
  __shared__ float stm[112];
  if (tid<112) stm[tid]=tm[(size_t)row*112+tid];
  __syncthreads();
  for (int c=tid;c<Cdim;c+=256){
    float m0=0.f,m1=0.f,m2=0.f,m3=0.f;
    #pragma unroll 7
    for (int d=0; d<28; d++){
      m0 += stm[d]    * w2[(size_t)(d)*Cdim + c];
      m1 += stm[28+d] * w2[(size_t)(28+d)*Cdim + c];
      m2 += stm[56+d] * w2[(size_t)(56+d)*Cdim + c];
      m3 += stm[84+d] * w2[(size_t)(84+d)*Cdim + c];
    }
    size_t i=(size_t)row*Cdim+c;
    float xval=x[i], d_=xx[i];
    xrg[i]=__float2bfloat16(xval + d_*(mrg[c]+m0));
    xwa[i]=__float2bfloat16(xval + d_*(mwa[c]+m1));
    xk[i] =__float2bfloat16(xval + d_*(mk_[c]+m2));
    xv[i] =__float2bfloat16(xval + d_*(mv_[c]+m3));
  }
}

// ---------------- K5: fused second-stage small gemms + elementwise + kk-normalize ----------------
__global__ __launch_bounds__(256) void k5_fuse(
    const float* __restrict__ h1, const float* __restrict__ h2, const float* __restrict__ h3,
    const float* __restrict__ h4, const float* __restrict__ h5, const float* __restrict__ h6,
    const float* __restrict__ h7,
    const float* __restrict__ dw2, const float* __restrict__ aaa_w2, const float* __restrict__ kkk_w2,
    const float* __restrict__ gate_w2, const float* __restrict__ ma_w2, const float* __restrict__ mk_w2,
    const float* __restrict__ mv_w2,
    const float* __restrict__ time_decay, const float* __restrict__ time_aaaaa,
    const float* __restrict__ misc_a, const float* __restrict__ misc_k, const float* __restrict__ misc_v,
    const float* __restrict__ v1,
    float* __restrict__ kbuf, float* __restrict__ vbuf, float* __restrict__ wexp,
    float* __restrict__ g, float* __restrict__ akv, float* __restrict__ bkv) {
  const int row = blockIdx.x, tid = threadIdx.x;
  __shared__ float s1[64], s2[24], s3[24], s4[120], s5[24], s6[24], s7[24];
  __shared__ float kkp[Cdim], aarr[Cdim];
  __shared__ float hinv[Hdim];
  if (tid<64)  s1[tid]=h1[(size_t)row*64+tid];
  if (tid<24){ s2[tid]=h2[(size_t)row*24+tid]; s3[tid]=h3[(size_t)row*24+tid];
               s5[tid]=h5[(size_t)row*24+tid]; s6[tid]=h6[(size_t)row*24+tid];
               s7[tid]=h7[(size_t)row*24+tid]; }
  if (tid>=128 && tid<248) s4[tid-128]=h4[(size_t)row*120+(tid-128)];
  __syncthreads();
  for (int c=tid;c<Cdim;c+=256){
    size_t i = (size_t)row*Cdim + c;
    float zd = time_decay[c];
    #pragma unroll 8
    for (int q=0;q<64;q++) zd += s1[q]*dw2[q*Cdim+c];
    float w = -softplusf(-zd) - 0.5f;
    wexp[i] = expf(-expf(w));
    float za = time_aaaaa[c];
    float zkk = 0.f, zg=0.f, zma=misc_a[c], zmk=misc_k[c], zmv=misc_v[c];
    #pragma unroll 8
    for (int q=0;q<24;q++){
      za  += s2[q]*aaa_w2[q*Cdim+c];
      zkk += s3[q]*kkk_w2[q*Cdim+c];
      zma += s5[q]*ma_w2[q*Cdim+c];
      zmk += s6[q]*mk_w2[q*Cdim+c];
      zmv += s7[q]*mv_w2[q*Cdim+c];
    }
    #pragma unroll 8
    for (int q=0;q<120;q++) zg += s4[q]*gate_w2[q*Cdim+c];
    float a = sigm(za);
    float kraw = kbuf[i];
    kkp[c] = kraw + zkk;
    aarr[c] = a;
    g[i] = zg;
    float ma = sigm(zma), mk = sigm(zmk), mv = sigm(zmv);
    float v0 = vbuf[i];
    vbuf[i] = v0 + (v1[i]-v0)*mv;
    float k1 = kraw*(ma + a*(1.f-ma));
    kbuf[i] = k1 * expf(fminf(w*mk, 0.f));
  }
  __syncthreads();
  if (tid < Hdim){
    float s=0.f;
    #pragma unroll
    for (int j=0;j<Ndim;j++){ float q=kkp[tid*Ndim+j]; s += q*q; }
    hinv[tid] = 1.f / fmaxf(sqrtf(s), 1e-12f);
  }
  __syncthreads();
  for (int c=tid;c<Cdim;c+=256){
    size_t i = (size_t)row*Cdim + c;
    float kkn = kkp[c]*hinv[c>>5];
    akv[i] = -kkn;
    bkv[i] = kkn*aarr[c];
  }
}

// ---------------- K6: WKV7 recurrence, chunked LDS staging, 1 wave (2 heads) per block ----------------
__global__ __launch_bounds__(64) void k6_wkv(const float* __restrict__ r, const float* __restrict__ wd,
    const float* __restrict__ k, const float* __restrict__ v,
    const float* __restrict__ a, const float* __restrict__ b2, float* __restrict__ y) {
  const int h01 = threadIdx.x >> 5;
  const int i = threadIdx.x & 31;
  const int head = blockIdx.x*2 + h01;
  const int bb = head / Hdim, hh = head - bb*Hdim;
  __shared__ __align__(16) float sb[2][2][6][CH][32];   // [buf][head01][arr][t][i]
  float S[Ndim];
  #pragma unroll
  for (int j=0;j<Ndim;j++) S[j]=0.f;
  const size_t base = ((size_t)bb*Tdim)*Cdim + (size_t)hh*Ndim + i;
  float pf0[CH], pf1[CH], pf2[CH], pf3[CH], pf4[CH], pf5[CH];

  auto LOADC = [&](int c0){
    size_t o = base + (size_t)c0*(CH*Cdim);
    #pragma unroll
    for (int t=0;t<CH;t++){
      size_t oo = o + (size_t)t*Cdim;
      pf0[t]=r[oo]; pf1[t]=wd[oo]; pf2[t]=k[oo]; pf3[t]=v[oo]; pf4[t]=a[oo]; pf5[t]=b2[oo];
    }
  };
  auto STOREC = [&](int buf){
    #pragma unroll
    for (int t=0;t<CH;t++){
      sb[buf][h01][0][t][i]=pf0[t]; sb[buf][h01][1][t][i]=pf1[t]; sb[buf][h01][2][t][i]=pf2[t];
      sb[buf][h01][3][t][i]=pf3[t]; sb[buf][h01][4][t][i]=pf4[t]; sb[buf][h01][5][t][i]=pf5[t];
    }
  };

  LOADC(0); STOREC(0);
  int cur = 0;
  const int NCH = Tdim/CH;
  for (int c=0; c<NCH; ++c){
    if (c+1 < NCH) LOADC(c+1);          // issue global loads early (T14)
    #pragma unroll 2
    for (int t=0;t<CH;t++){
      const float4* r4=(const float4*)&sb[cur][h01][0][t][0];
      const float4* w4=(const float4*)&sb[cur][h01][1][t][0];
      const float4* k4=(const float4*)&sb[cur][h01][2][t][0];
      const float4* a4=(const float4*)&sb[cur][h01][4][t][0];
      const float4* b4=(const float4*)&sb[cur][h01][5][t][0];
      float vloc = sb[cur][h01][3][t][i];
      float s0=0.f,s1=0.f,s2=0.f,s3=0.f;
      #pragma unroll
      for (int jj=0;jj<8;jj++){
        float4 aa=a4[jj];
        s0 += S[jj*4+0]*aa.x; s1 += S[jj*4+1]*aa.y;
        s2 += S[jj*4+2]*aa.z; s3 += S[jj*4+3]*aa.w;
      }
      float sav=(s0+s1)+(s2+s3);
      float y0=0.f,y1=0.f,y2=0.f,y3=0.f;
      #pragma unroll
      for (int jj=0;jj<8;jj++){
        float4 ww=w4[jj], kk=k4[jj], bb4=b4[jj], rr=r4[jj];
        float t0,t1,t2,t3;
        t0 = S[jj*4+0]*ww.x + (sav*bb4.x + vloc*kk.x);
        t1 = S[jj*4+1]*ww.y + (sav*bb4.y + vloc*kk.y);
        t2 = S[jj*4+2]*ww.z + (sav*bb4.z + vloc*kk.z);
        t3 = S[jj*4+3]*ww.w + (sav*bb4.w + vloc*kk.w);
        S[jj*4+0]=t0; S[jj*4+1]=t1; S[jj*4+2]=t2; S[jj*4+3]=t3;
        y0 += t0*rr.x; y1 += t1*rr.y; y2 += t2*rr.z; y3 += t3*rr.w;
      }
      y[base + (size_t)(c*CH+t)*Cdim] = (y0+y1)+(y2+y3);
    }
    if (c+1 < NCH) STOREC(cur^1);       // LDS write late: vmcnt wait lands here, after compute
    cur ^= 1;
  }
}

// ---------------- K7: GroupNorm + bonus + gate -> bf16 ----------------
__global__ __launch_bounds__(256) void k7_post(const float* __restrict__ y,
    const float* __restrict__ r, const float* __restrict__ kf, const float* __restrict__ v,
    const float* __restrict__ g, const float* __restrict__ faaaa,
    const float* __restrict__ lnw, const float* __restrict__ lnb,
    __hip_bfloat16* __restrict__ ygate) {
  const int row = blockIdx.x, tid = threadIdx.x;
  __shared__ float sy[Cdim], srk[Cdim];
  __shared__ float smu[Hdim], srs[Hdim], sbon[Hdim];
  for (int c=tid;c<Cdim;c+=256){
    size_t i=(size_t)row*Cdim+c;
    float yv=y[i]; sy[c]=yv;
    srk[c]=r[i]*kf[i]*faaaa[c];
  }
  __syncthreads();
  if (tid<Hdim){
    float s=0.f,ss=0.f,bn=0.f;
    #pragma unroll
    for (int j=0;j<Ndim;j++){
      float q=sy[tid*Ndim+j]; s+=q; ss+=q*q; bn+=srk[tid*Ndim+j];
    }
    float mu=s*(1.f/Ndim);
    float var=ss*(1.f/Ndim)-mu*mu;
    smu[tid]=mu; srs[tid]=rsqrtf(var+6.4e-5f); sbon[tid]=bn;
  }
  __syncthreads();
  for (int c=tid;c<Cdim;c+=256){
    size_t i=(size_t)row*Cdim+c; int h=c>>5;
    float yn=(sy[c]-smu[h])*srs[h]*lnw[c]+lnb[c];
    ygate[i]=__float2bfloat16((yn+sbon[h]*v[i])*g[i]);
  }
}

// ---------------- K9: v1 passthrough ----------------
__global__ void k9_copy(const float* __restrict__ src, float* __restrict__ dst){
  int idx = blockIdx.x*256 + threadIdx.x;
  if (idx < BTdim*Cdim) dst[idx]=src[idx];
}

extern "C" void kernel_launch(void* const* d_in, const int* in_sizes, int n_in,
                              void* d_out, int out_size, void* d_ws, size_t ws_size,
                              hipStream_t stream) {
  const float* x      = (const float*)d_in[0];
  const float* v1     = (const float*)d_in[1];
  const float* maa_x  = (const float*)d_in[2];
  const float* maa_rg = (const float*)d_in[3];
  const float* maa_wa = (const float*)d_in[4];
  const float* maa_k  = (const float*)d_in[5];
  const float* maa_v  = (const float*)d_in[6];
  const float* time_decay = (const float*)d_in[7];
  const float* faaaa  = (const float*)d_in[8];
  const float* aaaaa  = (const float*)d_in[9];
  const float* maa_w1 = (const float*)d_in[10];
  const float* maa_w2 = (const float*)d_in[11];
  const float* dw1    = (const float*)d_in[12];
  const float* dw2    = (const float*)d_in[13];
  const float* aaa_w1 = (const float*)d_in[14];
  const float* aaa_w2 = (const float*)d_in[15];
  const float* kkk_w1 = (const float*)d_in[16];
  const float* kkk_w2 = (const float*)d_in[17];
  const float* gate_w1= (const float*)d_in[18];
  const float* gate_w2= (const float*)d_in[19];
  const float* ma_w1  = (const float*)d_in[20];
  const float* ma_w2  = (const float*)d_in[21];
  const float* misc_a = (const float*)d_in[22];
  const float* mk_w1  = (const float*)d_in[23];
  const float* mk_w2  = (const float*)d_in[24];
  const float* misc_k = (const float*)d_in[25];
  const float* mv_w1  = (const float*)d_in[26];
  const float* mv_w2  = (const float*)d_in[27];
  const float* misc_v = (const float*)d_in[28];
  const float* Wr     = (const float*)d_in[29];
  const float* Wk     = (const float*)d_in[30];
  const float* Wv     = (const float*)d_in[31];
  const float* Wo     = (const float*)d_in[32];
  const float* lnw    = (const float*)d_in[33];
  const float* lnb    = (const float*)d_in[34];
  float* out = (float*)d_out;

  float* ws = (float*)d_ws;
  const size_t BTC = (size_t)BTdim*Cdim;
  float* ws0 = ws + 0*BTC;   // xx -> ybuf
  float* ws1 = ws + 1*BTC;   // xxx -> {xrg_bf,xwa_bf} -> akv -> yg_bf
  float* ws2 = ws + 2*BTC;   // {xk_bf,xv_bf} -> bkv
  float* rb  = ws + 3*BTC;
  float* kb  = ws + 4*BTC;
  float* vb  = ws + 5*BTC;
  float* wexp= ws + 6*BTC;
  float* gb  = ws + 7*BTC;
  float* S0  = ws + 8*BTC;
  float* tm  = S0;                          // BTdim*112 = 917504
  float* h1  = S0 + 917504;                 // *64
  float* h2  = h1 + 524288;                 // *24
  float* h3  = h2 + 196608;
  float* h4  = h3 + 196608;                 // *120
  float* h5  = h4 + 983040;
  float* h6  = h5 + 196608;
  float* h7  = h6 + 196608;
  __hip_bfloat16* WtR = (__hip_bfloat16*)(h7 + 196608);   // each 589824 bf16 = 294912 f32
  __hip_bfloat16* WtK = WtR + 589824;
  __hip_bfloat16* WtV = WtK + 589824;
  __hip_bfloat16* WtO = WtV + 589824;

  float* xx  = ws0;
  float* xxx = ws1;
  __hip_bfloat16* xrg_bf = (__hip_bfloat16*)ws1;
  __hip_bfloat16* xwa_bf = xrg_bf + BTC;
  __hip_bfloat16* xk_bf  = (__hip_bfloat16*)ws2;
  __hip_bfloat16* xv_bf  = xk_bf + BTC;
  float* akv = ws1;
  float* bkv = ws2;
  float* ybuf = ws0;
  __hip_bfloat16* yg_bf = (__hip_bfloat16*)ws1;

  dim3 blk(256);
  kconvW<<<dim3(24,24,4), blk, 0, stream>>>(Wr,Wk,Wv,Wo, WtR,WtK,WtV,WtO);
  k1_shift<<<dim3((BTdim*Cdim+255)/256), blk, 0, stream>>>(x, maa_x, xx, xxx);
  gemm_f32<1,float><<<dim3(2,128), blk, 0, stream>>>(xxx, maa_w1, tm, BTdim, Cdim, 112);
  k2_mix<<<dim3(BTdim), blk, 0, stream>>>(x, xx, tm, maa_w2, maa_rg, maa_wa, maa_k, maa_v,
                                          xrg_bf, xwa_bf, xk_bf, xv_bf);
  gemm_mfma<<<dim3(6,64), blk, 0, stream>>>(xrg_bf, WtR, rb, BTdim, Cdim, Cdim);
  gemm_mfma<<<dim3(6,64), blk, 0, stream>>>(xk_bf,  WtK, kb, BTdim, Cdim, Cdim);
  gemm_mfma<<<dim3(6,64), blk, 0, stream>>>(xv_bf,  WtV, vb, BTdim, Cdim, Cdim);
  gemm_f32<1,__hip_bfloat16><<<dim3(1,128), blk, 0, stream>>>(xwa_bf, dw1,    h1, BTdim, Cdim, 64);
  gemm_f32<0,__hip_bfloat16><<<dim3(1,128), blk, 0, stream>>>(xwa_bf, aaa_w1, h2, BTdim, Cdim, 24);
  gemm_f32<1,__hip_bfloat16><<<dim3(1,128), blk, 0, stream>>>(xk_bf,  kkk_w1, h3, BTdim, Cdim, 24);
  gemm_f32<2,__hip_bfloat16><<<dim3(2,128), blk, 0, stream>>>(xrg_bf, gate_w1,h4, BTdim, Cdim, 120);
  gemm_f32<0,__hip_bfloat16><<<dim3(1,128), blk, 0, stream>>>(xwa_bf, ma_w1,  h5, BTdim, Cdim, 24);
  gemm_f32<0,__hip_bfloat16><<<dim3(1,128), blk, 0, stream>>>(xk_bf,  mk_w1,  h6, BTdim, Cdim, 24);
  gemm_f32<0,__hip_bfloat16><<<dim3(1,128), blk, 0, stream>>>(xv_bf,  mv_w1,  h7, BTdim, Cdim, 24);
  k5_fuse<<<dim3(BTdim), blk, 0, stream>>>(h1,h2,h3,h4,h5,h6,h7,
      dw2,aaa_w2,kkk_w2,gate_w2,ma_w2,mk_w2,mv_w2,
      time_decay, aaaaa, misc_a, misc_k, misc_v, v1,
      kb, vb, wexp, gb, akv, bkv);
  k6_wkv<<<dim3(Bdim*Hdim/2), dim3(64), 0, stream>>>(rb, wexp, kb, vb, akv, bkv, ybuf);
  k7_post<<<dim3(BTdim), blk, 0, stream>>>(ybuf, rb, kb, vb, gb, faaaa, lnw, lnb, yg_bf);
  gemm_mfma<<<dim3(6,64), blk, 0, stream>>>(yg_bf, WtO, out, BTdim, Cdim, Cdim);
  k9_copy<<<dim3((BTdim*Cdim+255)/256), blk, 0, stream>>>(v1, out + BTC);
}

// Round 3
// 1389.700 us; speedup vs baseline: 1.8652x; 1.5222x over previous
//
#include <hip/hip_runtime.h>
#include <hip/hip_bf16.h>
#include <math.h>

#define Bdim 8
#define Tdim 1024
#define Cdim 768
#define Hdim 24
#define Ndim 32
#define BTdim (Bdim*Tdim)
#define CH6 16

typedef __attribute__((ext_vector_type(8))) short bf16x8;
typedef __attribute__((ext_vector_type(4))) float f32x4;

__device__ __forceinline__ float sigm(float x){ return 1.f/(1.f+expf(-x)); }
__device__ __forceinline__ float softplusf(float x){ return fmaxf(x,0.f) + log1pf(expf(-fabsf(x))); }

#define GLDS16(gp, lp) __builtin_amdgcn_global_load_lds((const __attribute__((address_space(1))) void*)(gp), (__attribute__((address_space(3))) void*)(lp), 16, 0, 0)

// ---------------- K1: token shift (xxx written bf16 for MFMA-ready maa gemm) ----------------
__global__ void k1_shift(const float* __restrict__ x, const float* __restrict__ maa_x,
                         float* __restrict__ xx, __hip_bfloat16* __restrict__ xxx) {
  int idx = blockIdx.x*256 + threadIdx.x;
  if (idx >= BTdim*Cdim) return;
  int c = idx % Cdim; int row = idx / Cdim; int t = row % Tdim;
  float xv = x[idx];
  float xp = (t==0) ? 0.f : x[idx - Cdim];
  float d = xp - xv;
  xx[idx] = d;
  xxx[idx] = __float2bfloat16(xv + d*maa_x[c]);
}

// ---------------- weight convert + transpose: Wt[n][k] = bf16(W[k][n]) ----------------
__global__ __launch_bounds__(256) void kconvW(const float* __restrict__ W0, const float* __restrict__ W1,
    const float* __restrict__ W2, const float* __restrict__ W3,
    __hip_bfloat16* __restrict__ T0, __hip_bfloat16* __restrict__ T1,
    __hip_bfloat16* __restrict__ T2, __hip_bfloat16* __restrict__ T3) {
  const float* Wsrc[4] = {W0,W1,W2,W3};
  __hip_bfloat16* Tdst[4] = {T0,T1,T2,T3};
  const float* W = Wsrc[blockIdx.z];
  __hip_bfloat16* T = Tdst[blockIdx.z];
  __shared__ float tile[32][33];
  int bx = blockIdx.x*32, by = blockIdx.y*32;
  int tx = threadIdx.x & 31, ty = threadIdx.x >> 5;
  #pragma unroll
  for (int q=0;q<32;q+=8) tile[ty+q][tx] = W[(size_t)(by+ty+q)*Cdim + bx+tx];
  __syncthreads();
  #pragma unroll
  for (int q=0;q<32;q+=8) T[(size_t)(bx+ty+q)*Cdim + by+tx] = __float2bfloat16(tile[tx][ty+q]);
}

// ---------------- generic small GEMM: O = act(A[M,K] @ W[K,N]) ----------------
template<int ACT, typename TA>
__global__ __launch_bounds__(256) void gemm_f32(const TA* __restrict__ A,
    const float* __restrict__ W, float* __restrict__ O, int M, int K, int N) {
  __shared__ float As[16][68];
  __shared__ float Ws[16][68];
  const int bm = blockIdx.y*64, bn = blockIdx.x*64;
  const int tid = threadIdx.x;
  const int tm0 = (tid>>4)<<2, tn0 = (tid&15)<<2;
  float acc[4][4] = {};
  for (int k0=0; k0<K; k0+=16) {
    #pragma unroll
    for (int i=0;i<4;i++){
      int l = tid + i*256;
      int m = l>>4, kk = l&15;
      As[kk][m] = (float)A[(size_t)(bm+m)*K + k0+kk];
    }
    #pragma unroll
    for (int i=0;i<4;i++){
      int l = tid + i*256;
      int kk = l>>6, n = l&63;
      Ws[kk][n] = (bn+n < N) ? W[(size_t)(k0+kk)*N + bn+n] : 0.f;
    }
    __syncthreads();
    #pragma unroll
    for (int kk=0;kk<16;kk++){
      float4 a4 = *(const float4*)&As[kk][tm0];
      float4 b4 = *(const float4*)&Ws[kk][tn0];
      float av[4]={a4.x,a4.y,a4.z,a4.w}, bv[4]={b4.x,b4.y,b4.z,b4.w};
      #pragma unroll
      for (int i=0;i<4;i++)
        #pragma unroll
        for (int j=0;j<4;j++)
          acc[i][j] += av[i]*bv[j];
    }
    __syncthreads();
  }
  #pragma unroll
  for (int i=0;i<4;i++){
    int m = bm+tm0+i;
    #pragma unroll
    for (int j=0;j<4;j++){
      int n = bn+tn0+j;
      if (n < N) {
        float v = acc[i][j];
        if (ACT==1) v = tanhf(v);
        else if (ACT==2) v = sigm(v);
        O[(size_t)m*N + n] = v;
      }
    }
  }
}

// ---------------- bf16 MFMA GEMM (m97 structure) ----------------
__global__ __launch_bounds__(256) void gemm_mfma(const __hip_bfloat16* __restrict__ A,
    const __hip_bfloat16* __restrict__ Bt, float* __restrict__ C, int M, int N, int K) {
  __shared__ unsigned short As[128*32];
  __shared__ unsigned short Bs[128*32];
  const int bm = blockIdx.y*128, bn = blockIdx.x*128;
  const int tid = threadIdx.x, lane = tid&63, w = tid>>6;
  const int wr = w>>1, wc = w&1;
  const int lr = lane&15, kg = lane>>4;
  f32x4 zero = {0.f,0.f,0.f,0.f};
  f32x4 acc[4][4];
  #pragma unroll
  for (int m=0;m<4;m++)
    #pragma unroll
    for (int n=0;n<4;n++) acc[m][n]=zero;
  const size_t rowA = (size_t)(bm + w*32 + (lane>>2))*K + (lane&3)*8;
  const size_t rowB = (size_t)(bn + w*32 + (lane>>2))*K + (lane&3)*8;
  unsigned short* lA = As + w*32*32;
  unsigned short* lB = Bs + w*32*32;
  for (int k0=0; k0<K; k0+=32){
    GLDS16(A + rowA + k0,                 lA);
    GLDS16(A + rowA + k0 + (size_t)16*K,  lA + 512);
    GLDS16(Bt + rowB + k0,                lB);
    GLDS16(Bt + rowB + k0 + (size_t)16*K, lB + 512);
    __syncthreads();
    bf16x8 af[4], bfr[4];
    #pragma unroll
    for (int m=0;m<4;m++) af[m]  = *(const bf16x8*)(void*)(As + (wr*64+m*16+lr)*32 + kg*8);
    #pragma unroll
    for (int n=0;n<4;n++) bfr[n] = *(const bf16x8*)(void*)(Bs + (wc*64+n*16+lr)*32 + kg*8);
    #pragma unroll
    for (int m=0;m<4;m++)
      #pragma unroll
      for (int n=0;n<4;n++)
        acc[m][n] = __builtin_amdgcn_mfma_f32_16x16x32_bf16(af[m], bfr[n], acc[m][n], 0,0,0);
    __syncthreads();
  }
  #pragma unroll
  for (int m=0;m<4;m++)
    #pragma unroll
    for (int n=0;n<4;n++){
      size_t r0 = (size_t)(bm + wr*64 + m*16 + kg*4);
      int cc = bn + wc*64 + n*16 + lr;
      #pragma unroll
      for (int q=0;q<4;q++)
        C[(r0+q)*N + cc] = acc[m][n][q];
    }
}

// ---------------- K2b: mix, 8 rows per block (weight reuse x8) ----------------
__global__ __launch_bounds__(256) void k2_mix(const float* __restrict__ x, const float* __restrict__ xx,
    const float* __restrict__ tm, const float* __restrict__ w2,
    const float* __restrict__ mrg, const float* __restrict__ mwa,
    const float* __restrict__ mk_, const float* __restrict__ mv_,
    __hip_bfloat16* __restrict__ xrg, __hip_bfloat16* __restrict__ xwa,
    __hip_bfloat16* __restrict__ xk, __hip_bfloat16* __restrict__ xv) {
  const int row0 = blockIdx.x*8, tid = threadIdx.x;
  __shared__ float stm[8][112];
  for (int idx=tid; idx<8*112; idx+=256){
    int rr=idx/112, q=idx-rr*112;
    stm[rr][q]=tm[(size_t)(row0+rr)*112+q];
  }
  __syncthreads();
  for (int c=tid;c<Cdim;c+=256){
    float x8[8], d8[8];
    #pragma unroll
    for (int rr=0;rr<8;rr++){
      size_t i=(size_t)(row0+rr)*Cdim+c;
      x8[rr]=x[i]; d8[rr]=xx[i];
    }
    float mrgc=mrg[c], mwac=mwa[c], mkc=mk_[c], mvc=mv_[c];
    float m0[8]={},m1[8]={},m2[8]={},m3[8]={};
    #pragma unroll 4
    for (int d=0; d<28; d++){
      float w0=w2[(size_t)(d)*Cdim + c];
      float w1=w2[(size_t)(28+d)*Cdim + c];
      float w2v=w2[(size_t)(56+d)*Cdim + c];
      float w3=w2[(size_t)(84+d)*Cdim + c];
      #pragma unroll
      for (int rr=0;rr<8;rr++){
        m0[rr]+=stm[rr][d]*w0; m1[rr]+=stm[rr][28+d]*w1;
        m2[rr]+=stm[rr][56+d]*w2v; m3[rr]+=stm[rr][84+d]*w3;
      }
    }
    #pragma unroll
    for (int rr=0;rr<8;rr++){
      size_t i=(size_t)(row0+rr)*Cdim+c;
      xrg[i]=__float2bfloat16(x8[rr] + d8[rr]*(mrgc+m0[rr]));
      xwa[i]=__float2bfloat16(x8[rr] + d8[rr]*(mwac+m1[rr]));
      xk[i] =__float2bfloat16(x8[rr] + d8[rr]*(mkc+m2[rr]));
      xv[i] =__float2bfloat16(x8[rr] + d8[rr]*(mvc+m3[rr]));
    }
  }
}

// ---------------- K5: fused second-stage, 8 rows per block (weight reuse x8) ----------------
__global__ __launch_bounds__(256) void k5_fuse(
    const float* __restrict__ h1, const float* __restrict__ h2, const float* __restrict__ h3,
    const float* __restrict__ h4, const float* __restrict__ h5, const float* __restrict__ h6,
    const float* __restrict__ h7,
    const float* __restrict__ dw2, const float* __restrict__ aaa_w2, const float* __restrict__ kkk_w2,
    const float* __restrict__ gate_w2, const float* __restrict__ ma_w2, const float* __restrict__ mk_w2,
    const float* __restrict__ mv_w2,
    const float* __restrict__ time_decay, const float* __restrict__ time_aaaaa,
    const float* __restrict__ misc_a, const float* __restrict__ misc_k, const float* __restrict__ misc_v,
    const float* __restrict__ v1,
    float* __restrict__ kbuf, float* __restrict__ vbuf, float* __restrict__ wexp,
    float* __restrict__ g, float* __restrict__ akv, float* __restrict__ bkv) {
  const int row0 = blockIdx.x*8, tid = threadIdx.x;
  __shared__ float s1[8][64], s2[8][24], s3[8][24], s4[8][120], s5[8][24], s6[8][24], s7[8][24];
  __shared__ float kkp[8][Cdim];
  __shared__ float aar[8][Cdim];
  __shared__ float hv[8][Hdim];
  for (int idx=tid; idx<8*64; idx+=256){ int rr=idx>>6, q=idx&63; s1[rr][q]=h1[(size_t)(row0+rr)*64+q]; }
  for (int idx=tid; idx<8*24; idx+=256){
    int rr=idx/24, q=idx-rr*24;
    s2[rr][q]=h2[(size_t)(row0+rr)*24+q]; s3[rr][q]=h3[(size_t)(row0+rr)*24+q];
    s5[rr][q]=h5[(size_t)(row0+rr)*24+q]; s6[rr][q]=h6[(size_t)(row0+rr)*24+q];
    s7[rr][q]=h7[(size_t)(row0+rr)*24+q];
  }
  for (int idx=tid; idx<8*120; idx+=256){ int rr=idx/120, q=idx-rr*120; s4[rr][q]=h4[(size_t)(row0+rr)*120+q]; }
  __syncthreads();
  for (int c=tid;c<Cdim;c+=256){
    float kraw[8], w8[8], a8[8];
    #pragma unroll
    for (int rr=0;rr<8;rr++) kraw[rr]=kbuf[(size_t)(row0+rr)*Cdim+c];
    // decay
    {
      float zd[8];
      float tdc = time_decay[c];
      #pragma unroll
      for (int rr=0;rr<8;rr++) zd[rr]=tdc;
      #pragma unroll 8
      for (int q=0;q<64;q++){
        float wv=dw2[(size_t)q*Cdim+c];
        #pragma unroll
        for (int rr=0;rr<8;rr++) zd[rr]+=s1[rr][q]*wv;
      }
      #pragma unroll
      for (int rr=0;rr<8;rr++){
        float w = -softplusf(-zd[rr]) - 0.5f;
        w8[rr]=w;
        wexp[(size_t)(row0+rr)*Cdim+c]=expf(-expf(w));
      }
    }
    // a + kk
    {
      float za[8], zk[8];
      float aac = time_aaaaa[c];
      #pragma unroll
      for (int rr=0;rr<8;rr++){ za[rr]=aac; zk[rr]=0.f; }
      #pragma unroll 8
      for (int q=0;q<24;q++){
        float wa=aaa_w2[(size_t)q*Cdim+c], wk=kkk_w2[(size_t)q*Cdim+c];
        #pragma unroll
        for (int rr=0;rr<8;rr++){ za[rr]+=s2[rr][q]*wa; zk[rr]+=s3[rr][q]*wk; }
      }
      #pragma unroll
      for (int rr=0;rr<8;rr++){
        a8[rr]=sigm(za[rr]);
        aar[rr][c]=a8[rr];
        kkp[rr][c]=kraw[rr]+zk[rr];
      }
    }
    // gate
    {
      float zg[8]={};
      #pragma unroll 8
      for (int q=0;q<120;q++){
        float wv=gate_w2[(size_t)q*Cdim+c];
        #pragma unroll
        for (int rr=0;rr<8;rr++) zg[rr]+=s4[rr][q]*wv;
      }
      #pragma unroll
      for (int rr=0;rr<8;rr++) g[(size_t)(row0+rr)*Cdim+c]=zg[rr];
    }
    // ma, mk, mv + elementwise
    {
      float zma[8], zmk[8], zmv[8];
      float mac=misc_a[c], mkc=misc_k[c], mvc=misc_v[c];
      #pragma unroll
      for (int rr=0;rr<8;rr++){ zma[rr]=mac; zmk[rr]=mkc; zmv[rr]=mvc; }
      #pragma unroll 8
      for (int q=0;q<24;q++){
        float w5=ma_w2[(size_t)q*Cdim+c], w6=mk_w2[(size_t)q*Cdim+c], w7=mv_w2[(size_t)q*Cdim+c];
        #pragma unroll
        for (int rr=0;rr<8;rr++){ zma[rr]+=s5[rr][q]*w5; zmk[rr]+=s6[rr][q]*w6; zmv[rr]+=s7[rr][q]*w7; }
      }
      #pragma unroll
      for (int rr=0;rr<8;rr++){
        size_t i=(size_t)(row0+rr)*Cdim+c;
        float ma=sigm(zma[rr]), mk=sigm(zmk[rr]), mv=sigm(zmv[rr]);
        float v0=vbuf[i];
        vbuf[i]=v0+(v1[i]-v0)*mv;
        float k1=kraw[rr]*(ma + a8[rr]*(1.f-ma));
        kbuf[i]=k1*expf(fminf(w8[rr]*mk,0.f));
      }
    }
  }
  __syncthreads();
  for (int idx=tid; idx<8*Hdim; idx+=256){
    int rr=idx/Hdim, hh=idx-rr*Hdim;
    float s=0.f;
    #pragma unroll
    for (int j=0;j<Ndim;j++){ float q=kkp[rr][hh*Ndim+j]; s+=q*q; }
    hv[rr][hh]=1.f/fmaxf(sqrtf(s),1e-12f);
  }
  __syncthreads();
  for (int c=tid;c<Cdim;c+=256){
    #pragma unroll
    for (int rr=0;rr<8;rr++){
      size_t i=(size_t)(row0+rr)*Cdim+c;
      float kkn=kkp[rr][c]*hv[rr][c>>5];
      akv[i]=-kkn;
      bkv[i]=kkn*aar[rr][c];
    }
  }
}

// ---------------- K6 v3: WKV7, GLDS staging + 4-way j-split ----------------
// Block = 256 threads = 2 heads. Per head 128 lanes: row i = (tid&127)>>2, jq = tid&3.
// Lane owns S[i][jq*8 .. jq*8+8). Quad shfl_xor(1,2) for sa / y reductions.
// Wave 0 stages CH6 timesteps of all 6 streams (both heads, 64 contiguous floats/row)
// into LDS via global_load_lds (zero VGPR cost); one barrier per chunk drains vmcnt.
__global__ __launch_bounds__(256) void k6_wkv(const float* __restrict__ r, const float* __restrict__ wd,
    const float* __restrict__ k, const float* __restrict__ v,
    const float* __restrict__ a, const float* __restrict__ b2, float* __restrict__ y) {
  const int tid = threadIdx.x;
  const int h01 = tid >> 7;
  const int i = (tid & 127) >> 2;
  const int jq = tid & 3;
  const int head0 = blockIdx.x*2;
  const int bb = head0 / Hdim;
  const int hh0 = head0 - bb*Hdim;
  __shared__ __align__(16) float sb[2][6][CH6][64];
  const float* gptr[6] = {r, wd, k, v, a, b2};
  // global base: both heads' 64 contiguous columns
  const size_t gbase = (size_t)bb*Tdim*Cdim + (size_t)hh0*Ndim;
  float S[8];
  #pragma unroll
  for (int m=0;m<8;m++) S[m]=0.f;
  const size_t ybase = gbase + (size_t)h01*Ndim + i;
  const int col = h01*32 + jq*8;
  const int vcol = h01*32 + i;
  const int l = tid;                 // staging lane (only tid<64 stages)
  const int trow = l >> 4;           // 4 timesteps per GLDS16
  const int c4 = (l & 15) * 4;

  auto STAGE = [&](int c, int buf){
    const size_t tb = (size_t)c*CH6;
    #pragma unroll
    for (int arr=0; arr<6; arr++){
      const float* gp = gptr[arr] + gbase;
      #pragma unroll
      for (int tg=0; tg<CH6/4; tg++){
        GLDS16(gp + (tb + tg*4 + trow)*Cdim + c4, &sb[buf][arr][tg*4][0]);
      }
    }
  };

  if (tid < 64) STAGE(0, 0);
  __syncthreads();
  int cur = 0;
  const int NCH = Tdim/CH6;
  for (int c=0; c<NCH; ++c){
    if (tid < 64 && c+1 < NCH) STAGE(c+1, cur^1);
    #pragma unroll
    for (int t=0; t<CH6; t++){
      const float4 aa0 = *(const float4*)&sb[cur][4][t][col];
      const float4 aa1 = *(const float4*)&sb[cur][4][t][col+4];
      float sa = (S[0]*aa0.x + S[1]*aa0.y + S[2]*aa0.z + S[3]*aa0.w)
               + (S[4]*aa1.x + S[5]*aa1.y + S[6]*aa1.z + S[7]*aa1.w);
      sa += __shfl_xor(sa, 1);
      sa += __shfl_xor(sa, 2);
      const float4 ww0 = *(const float4*)&sb[cur][1][t][col];
      const float4 ww1 = *(const float4*)&sb[cur][1][t][col+4];
      const float4 kk0 = *(const float4*)&sb[cur][2][t][col];
      const float4 kk1 = *(const float4*)&sb[cur][2][t][col+4];
      const float4 bb0 = *(const float4*)&sb[cur][5][t][col];
      const float4 bb1 = *(const float4*)&sb[cur][5][t][col+4];
      const float4 rr0 = *(const float4*)&sb[cur][0][t][col];
      const float4 rr1 = *(const float4*)&sb[cur][0][t][col+4];
      const float vloc = sb[cur][3][t][vcol];
      S[0] = S[0]*ww0.x + (sa*bb0.x + vloc*kk0.x);
      S[1] = S[1]*ww0.y + (sa*bb0.y + vloc*kk0.y);
      S[2] = S[2]*ww0.z + (sa*bb0.z + vloc*kk0.z);
      S[3] = S[3]*ww0.w + (sa*bb0.w + vloc*kk0.w);
      S[4] = S[4]*ww1.x + (sa*bb1.x + vloc*kk1.x);
      S[5] = S[5]*ww1.y + (sa*bb1.y + vloc*kk1.y);
      S[6] = S[6]*ww1.z + (sa*bb1.z + vloc*kk1.z);
      S[7] = S[7]*ww1.w + (sa*bb1.w + vloc*kk1.w);
      float yp = (S[0]*rr0.x + S[1]*rr0.y + S[2]*rr0.z + S[3]*rr0.w)
               + (S[4]*rr1.x + S[5]*rr1.y + S[6]*rr1.z + S[7]*rr1.w);
      yp += __shfl_xor(yp, 1);
      yp += __shfl_xor(yp, 2);
      if (jq == 0) y[ybase + (size_t)(c*CH6+t)*Cdim] = yp;
    }
    __syncthreads();
    cur ^= 1;
  }
}

// ---------------- K7: GroupNorm + bonus + gate -> bf16 ----------------
__global__ __launch_bounds__(256) void k7_post(const float* __restrict__ y,
    const float* __restrict__ r, const float* __restrict__ kf, const float* __restrict__ v,
    const float* __restrict__ g, const float* __restrict__ faaaa,
    const float* __restrict__ lnw, const float* __restrict__ lnb,
    __hip_bfloat16* __restrict__ ygate) {
  const int row = blockIdx.x, tid = threadIdx.x;
  __shared__ float sy[Cdim], srk[Cdim];
  __shared__ float smu[Hdim], srs[Hdim], sbon[Hdim];
  for (int c=tid;c<Cdim;c+=256){
    size_t i=(size_t)row*Cdim+c;
    float yv=y[i]; sy[c]=yv;
    srk[c]=r[i]*kf[i]*faaaa[c];
  }
  __syncthreads();
  if (tid<Hdim){
    float s=0.f,ss=0.f,bn=0.f;
    #pragma unroll
    for (int j=0;j<Ndim;j++){
      float q=sy[tid*Ndim+j]; s+=q; ss+=q*q; bn+=srk[tid*Ndim+j];
    }
    float mu=s*(1.f/Ndim);
    float var=ss*(1.f/Ndim)-mu*mu;
    smu[tid]=mu; srs[tid]=rsqrtf(var+6.4e-5f); sbon[tid]=bn;
  }
  __syncthreads();
  for (int c=tid;c<Cdim;c+=256){
    size_t i=(size_t)row*Cdim+c; int h=c>>5;
    float yn=(sy[c]-smu[h])*srs[h]*lnw[c]+lnb[c];
    ygate[i]=__float2bfloat16((yn+sbon[h]*v[i])*g[i]);
  }
}

// ---------------- K9: v1 passthrough ----------------
__global__ void k9_copy(const float* __restrict__ src, float* __restrict__ dst){
  int idx = blockIdx.x*256 + threadIdx.x;
  if (idx < BTdim*Cdim) dst[idx]=src[idx];
}

extern "C" void kernel_launch(void* const* d_in, const int* in_sizes, int n_in,
                              void* d_out, int out_size, void* d_ws, size_t ws_size,
                              hipStream_t stream) {
  const float* x      = (const float*)d_in[0];
  const float* v1     = (const float*)d_in[1];
  const float* maa_x  = (const float*)d_in[2];
  const float* maa_rg = (const float*)d_in[3];
  const float* maa_wa = (const float*)d_in[4];
  const float* maa_k  = (const float*)d_in[5];
  const float* maa_v  = (const float*)d_in[6];
  const float* time_decay = (const float*)d_in[7];
  const float* faaaa  = (const float*)d_in[8];
  const float* aaaaa  = (const float*)d_in[9];
  const float* maa_w1 = (const float*)d_in[10];
  const float* maa_w2 = (const float*)d_in[11];
  const float* dw1    = (const float*)d_in[12];
  const float* dw2    = (const float*)d_in[13];
  const float* aaa_w1 = (const float*)d_in[14];
  const float* aaa_w2 = (const float*)d_in[15];
  const float* kkk_w1 = (const float*)d_in[16];
  const float* kkk_w2 = (const float*)d_in[17];
  const float* gate_w1= (const float*)d_in[18];
  const float* gate_w2= (const float*)d_in[19];
  const float* ma_w1  = (const float*)d_in[20];
  const float* ma_w2  = (const float*)d_in[21];
  const float* misc_a = (const float*)d_in[22];
  const float* mk_w1  = (const float*)d_in[23];
  const float* mk_w2  = (const float*)d_in[24];
  const float* misc_k = (const float*)d_in[25];
  const float* mv_w1  = (const float*)d_in[26];
  const float* mv_w2  = (const float*)d_in[27];
  const float* misc_v = (const float*)d_in[28];
  const float* Wr     = (const float*)d_in[29];
  const float* Wk     = (const float*)d_in[30];
  const float* Wv     = (const float*)d_in[31];
  const float* Wo     = (const float*)d_in[32];
  const float* lnw    = (const float*)d_in[33];
  const float* lnb    = (const float*)d_in[34];
  float* out = (float*)d_out;

  float* ws = (float*)d_ws;
  const size_t BTC = (size_t)BTdim*Cdim;
  float* ws0 = ws + 0*BTC;   // xx -> ybuf
  float* ws1 = ws + 1*BTC;   // xxx_bf -> {xrg_bf,xwa_bf} -> akv -> yg_bf
  float* ws2 = ws + 2*BTC;   // {xk_bf,xv_bf} -> bkv
  float* rb  = ws + 3*BTC;
  float* kb  = ws + 4*BTC;
  float* vb  = ws + 5*BTC;
  float* wexp= ws + 6*BTC;
  float* gb  = ws + 7*BTC;
  float* S0  = ws + 8*BTC;
  float* tm  = S0;                          // BTdim*112
  float* h1  = S0 + 917504;                 // *64
  float* h2  = h1 + 524288;                 // *24
  float* h3  = h2 + 196608;
  float* h4  = h3 + 196608;                 // *120
  float* h5  = h4 + 983040;
  float* h6  = h5 + 196608;
  float* h7  = h6 + 196608;
  __hip_bfloat16* WtR = (__hip_bfloat16*)(h7 + 196608);
  __hip_bfloat16* WtK = WtR + 589824;
  __hip_bfloat16* WtV = WtK + 589824;
  __hip_bfloat16* WtO = WtV + 589824;

  float* xx  = ws0;
  __hip_bfloat16* xxx_bf = (__hip_bfloat16*)ws1;
  __hip_bfloat16* xrg_bf = (__hip_bfloat16*)ws1;
  __hip_bfloat16* xwa_bf = xrg_bf + BTC;
  __hip_bfloat16* xk_bf  = (__hip_bfloat16*)ws2;
  __hip_bfloat16* xv_bf  = xk_bf + BTC;
  float* akv = ws1;
  float* bkv = ws2;
  float* ybuf = ws0;
  __hip_bfloat16* yg_bf = (__hip_bfloat16*)ws1;

  dim3 blk(256);
  kconvW<<<dim3(24,24,4), blk, 0, stream>>>(Wr,Wk,Wv,Wo, WtR,WtK,WtV,WtO);
  k1_shift<<<dim3((BTdim*Cdim+255)/256), blk, 0, stream>>>(x, maa_x, xx, xxx_bf);
  gemm_f32<1,__hip_bfloat16><<<dim3(2,128), blk, 0, stream>>>(xxx_bf, maa_w1, tm, BTdim, Cdim, 112);
  k2_mix<<<dim3(BTdim/8), blk, 0, stream>>>(x, xx, tm, maa_w2, maa_rg, maa_wa, maa_k, maa_v,
                                            xrg_bf, xwa_bf, xk_bf, xv_bf);
  gemm_mfma<<<dim3(6,64), blk, 0, stream>>>(xrg_bf, WtR, rb, BTdim, Cdim, Cdim);
  gemm_mfma<<<dim3(6,64), blk, 0, stream>>>(xk_bf,  WtK, kb, BTdim, Cdim, Cdim);
  gemm_mfma<<<dim3(6,64), blk, 0, stream>>>(xv_bf,  WtV, vb, BTdim, Cdim, Cdim);
  gemm_f32<1,__hip_bfloat16><<<dim3(1,128), blk, 0, stream>>>(xwa_bf, dw1,    h1, BTdim, Cdim, 64);
  gemm_f32<0,__hip_bfloat16><<<dim3(1,128), blk, 0, stream>>>(xwa_bf, aaa_w1, h2, BTdim, Cdim, 24);
  gemm_f32<1,__hip_bfloat16><<<dim3(1,128), blk, 0, stream>>>(xk_bf,  kkk_w1, h3, BTdim, Cdim, 24);
  gemm_f32<2,__hip_bfloat16><<<dim3(2,128), blk, 0, stream>>>(xrg_bf, gate_w1,h4, BTdim, Cdim, 120);
  gemm_f32<0,__hip_bfloat16><<<dim3(1,128), blk, 0, stream>>>(xwa_bf, ma_w1,  h5, BTdim, Cdim, 24);
  gemm_f32<0,__hip_bfloat16><<<dim3(1,128), blk, 0, stream>>>(xk_bf,  mk_w1,  h6, BTdim, Cdim, 24);
  gemm_f32<0,__hip_bfloat16><<<dim3(1,128), blk, 0, stream>>>(xv_bf,  mv_w1,  h7, BTdim, Cdim, 24);
  k5_fuse<<<dim3(BTdim/8), blk, 0, stream>>>(h1,h2,h3,h4,h5,h6,h7,
      dw2,aaa_w2,kkk_w2,gate_w2,ma_w2,mk_w2,mv_w2,
      time_decay, aaaaa, misc_a, misc_k, misc_v, v1,
      kb, vb, wexp, gb, akv, bkv);
  k6_wkv<<<dim3(Bdim*Hdim/2), blk, 0, stream>>>(rb, wexp, kb, vb, akv, bkv, ybuf);
  k7_post<<<dim3(BTdim), blk, 0, stream>>>(ybuf, rb, kb, vb, gb, faaaa, lnw, lnb, yg_bf);
  gemm_mfma<<<dim3(6,64), blk, 0, stream>>>(yg_bf, WtO, out, BTdim, Cdim, Cdim);
  k9_copy<<<dim3((BTdim*Cdim+255)/256), blk, 0, stream>>>(v1, out + BTC);
}

// Round 4
// 849.996 us; speedup vs baseline: 3.0496x; 1.6349x over previous
//
#include <hip/hip_runtime.h>
#include <hip/hip_bf16.h>
#include <math.h>

#define Bdim 8
#define Tdim 1024
#define Cdim 768
#define Hdim 24
#define Ndim 32
#define BTdim (Bdim*Tdim)
#define CH6 16

typedef __attribute__((ext_vector_type(8))) short bf16x8;
typedef __attribute__((ext_vector_type(4))) float f32x4;

__device__ __forceinline__ float sigm(float x){ return 1.f/(1.f+expf(-x)); }
__device__ __forceinline__ float softplusf(float x){ return fmaxf(x,0.f) + log1pf(expf(-fabsf(x))); }

template<int CTRL>
__device__ __forceinline__ float dpp_add(float x){
  int xi = __builtin_bit_cast(int, x);
  int yi = __builtin_amdgcn_mov_dpp(xi, CTRL, 0xF, 0xF, true);
  return x + __builtin_bit_cast(float, yi);
}

#define GLDS16(gp, lp) __builtin_amdgcn_global_load_lds((const __attribute__((address_space(1))) void*)(gp), (__attribute__((address_space(3))) void*)(lp), 16, 0, 0)

// ---------------- K1: token shift ----------------
__global__ void k1_shift(const float* __restrict__ x, const float* __restrict__ maa_x,
                         float* __restrict__ xx, __hip_bfloat16* __restrict__ xxx) {
  int idx = blockIdx.x*256 + threadIdx.x;
  if (idx >= BTdim*Cdim) return;
  int c = idx % Cdim; int row = idx / Cdim; int t = row % Tdim;
  float xv = x[idx];
  float xp = (t==0) ? 0.f : x[idx - Cdim];
  float d = xp - xv;
  xx[idx] = d;
  xxx[idx] = __float2bfloat16(xv + d*maa_x[c]);
}

// ---------------- big weight convert + transpose: Wt[n][k] = bf16(W[k][n]) ----------------
__global__ __launch_bounds__(256) void kconvW(const float* __restrict__ W0, const float* __restrict__ W1,
    const float* __restrict__ W2, const float* __restrict__ W3,
    __hip_bfloat16* __restrict__ T0, __hip_bfloat16* __restrict__ T1,
    __hip_bfloat16* __restrict__ T2, __hip_bfloat16* __restrict__ T3) {
  const float* Wsrc[4] = {W0,W1,W2,W3};
  __hip_bfloat16* Tdst[4] = {T0,T1,T2,T3};
  const float* W = Wsrc[blockIdx.z];
  __hip_bfloat16* T = Tdst[blockIdx.z];
  __shared__ float tile[32][33];
  int bx = blockIdx.x*32, by = blockIdx.y*32;
  int tx = threadIdx.x & 31, ty = threadIdx.x >> 5;
  #pragma unroll
  for (int q=0;q<32;q+=8) tile[ty+q][tx] = W[(size_t)(by+ty+q)*Cdim + bx+tx];
  __syncthreads();
  #pragma unroll
  for (int q=0;q<32;q+=8) T[(size_t)(bx+ty+q)*Cdim + by+tx] = __float2bfloat16(tile[tx][ty+q]);
}

// ---------------- small-weight pack: transposed bf16 padded to [128][768] ----------------
__global__ __launch_bounds__(256) void kprep(const float* __restrict__ dw1, const float* __restrict__ aaa_w1,
    const float* __restrict__ ma_w1, const float* __restrict__ kkk_w1, const float* __restrict__ mk_w1,
    const float* __restrict__ mv_w1, const float* __restrict__ gate_w1, const float* __restrict__ maa_w1,
    __hip_bfloat16* __restrict__ PWwa, __hip_bfloat16* __restrict__ PWk, __hip_bfloat16* __restrict__ PWv,
    __hip_bfloat16* __restrict__ PWrg, __hip_bfloat16* __restrict__ PWmaa){
  int idx = blockIdx.x*256 + threadIdx.x;
  if (idx >= 5*128*768) return;
  int buf = idx / 98304, rem = idx - buf*98304;
  int n = rem / 768, kk = rem - n*768;
  float val = 0.f;
  __hip_bfloat16* dst;
  switch(buf){
    case 0: dst=PWwa; if(n<64) val=dw1[(size_t)kk*64+n]; else if(n<88) val=aaa_w1[(size_t)kk*24+(n-64)]; else if(n<112) val=ma_w1[(size_t)kk*24+(n-88)]; break;
    case 1: dst=PWk;  if(n<24) val=kkk_w1[(size_t)kk*24+n]; else if(n<48) val=mk_w1[(size_t)kk*24+(n-24)]; break;
    case 2: dst=PWv;  if(n<24) val=mv_w1[(size_t)kk*24+n]; break;
    case 3: dst=PWrg; if(n<120) val=gate_w1[(size_t)kk*120+n]; break;
    default: dst=PWmaa; if(n<112) val=maa_w1[(size_t)kk*112+n]; break;
  }
  dst[rem] = __float2bfloat16(val);
}

// ---------------- bf16 MFMA GEMM (m97 structure), arbitrary N<=grid*128 with C-mask ----------------
__global__ __launch_bounds__(256) void gemm_mfma(const __hip_bfloat16* __restrict__ A,
    const __hip_bfloat16* __restrict__ Bt, float* __restrict__ C, int M, int N, int K) {
  __shared__ unsigned short As[128*32];
  __shared__ unsigned short Bs[128*32];
  const int bm = blockIdx.y*128, bn = blockIdx.x*128;
  const int tid = threadIdx.x, lane = tid&63, w = tid>>6;
  const int wr = w>>1, wc = w&1;
  const int lr = lane&15, kg = lane>>4;
  f32x4 zero = {0.f,0.f,0.f,0.f};
  f32x4 acc[4][4];
  #pragma unroll
  for (int m=0;m<4;m++)
    #pragma unroll
    for (int n=0;n<4;n++) acc[m][n]=zero;
  const size_t rowA = (size_t)(bm + w*32 + (lane>>2))*K + (lane&3)*8;
  const size_t rowB = (size_t)(bn + w*32 + (lane>>2))*K + (lane&3)*8;
  unsigned short* lA = As + w*32*32;
  unsigned short* lB = Bs + w*32*32;
  for (int k0=0; k0<K; k0+=32){
    GLDS16(A + rowA + k0,                 lA);
    GLDS16(A + rowA + k0 + (size_t)16*K,  lA + 512);
    GLDS16(Bt + rowB + k0,                lB);
    GLDS16(Bt + rowB + k0 + (size_t)16*K, lB + 512);
    __syncthreads();
    bf16x8 af[4], bfr[4];
    #pragma unroll
    for (int m=0;m<4;m++) af[m]  = *(const bf16x8*)(void*)(As + (wr*64+m*16+lr)*32 + kg*8);
    #pragma unroll
    for (int n=0;n<4;n++) bfr[n] = *(const bf16x8*)(void*)(Bs + (wc*64+n*16+lr)*32 + kg*8);
    #pragma unroll
    for (int m=0;m<4;m++)
      #pragma unroll
      for (int n=0;n<4;n++)
        acc[m][n] = __builtin_amdgcn_mfma_f32_16x16x32_bf16(af[m], bfr[n], acc[m][n], 0,0,0);
    __syncthreads();
  }
  #pragma unroll
  for (int m=0;m<4;m++)
    #pragma unroll
    for (int n=0;n<4;n++){
      size_t r0 = (size_t)(bm + wr*64 + m*16 + kg*4);
      int cc = bn + wc*64 + n*16 + lr;
      if (cc < N) {
        #pragma unroll
        for (int q=0;q<4;q++)
          C[(r0+q)*N + cc] = acc[m][n][q];
      }
    }
}

// ---------------- K2b: mix, 8 rows per block (tanh applied to tm on load) ----------------
__global__ __launch_bounds__(256) void k2_mix(const float* __restrict__ x, const float* __restrict__ xx,
    const float* __restrict__ tm, const float* __restrict__ w2,
    const float* __restrict__ mrg, const float* __restrict__ mwa,
    const float* __restrict__ mk_, const float* __restrict__ mv_,
    __hip_bfloat16* __restrict__ xrg, __hip_bfloat16* __restrict__ xwa,
    __hip_bfloat16* __restrict__ xk, __hip_bfloat16* __restrict__ xv) {
  const int row0 = blockIdx.x*8, tid = threadIdx.x;
  __shared__ float stm[8][112];
  for (int idx=tid; idx<8*112; idx+=256){
    int rr=idx/112, q=idx-rr*112;
    stm[rr][q]=tanhf(tm[(size_t)(row0+rr)*112+q]);
  }
  __syncthreads();
  for (int c=tid;c<Cdim;c+=256){
    float x8[8], d8[8];
    #pragma unroll
    for (int rr=0;rr<8;rr++){
      size_t i=(size_t)(row0+rr)*Cdim+c;
      x8[rr]=x[i]; d8[rr]=xx[i];
    }
    float mrgc=mrg[c], mwac=mwa[c], mkc=mk_[c], mvc=mv_[c];
    float m0[8]={},m1[8]={},m2[8]={},m3[8]={};
    #pragma unroll 4
    for (int d=0; d<28; d++){
      float w0=w2[(size_t)(d)*Cdim + c];
      float w1=w2[(size_t)(28+d)*Cdim + c];
      float w2v=w2[(size_t)(56+d)*Cdim + c];
      float w3=w2[(size_t)(84+d)*Cdim + c];
      #pragma unroll
      for (int rr=0;rr<8;rr++){
        m0[rr]+=stm[rr][d]*w0; m1[rr]+=stm[rr][28+d]*w1;
        m2[rr]+=stm[rr][56+d]*w2v; m3[rr]+=stm[rr][84+d]*w3;
      }
    }
    #pragma unroll
    for (int rr=0;rr<8;rr++){
      size_t i=(size_t)(row0+rr)*Cdim+c;
      xrg[i]=__float2bfloat16(x8[rr] + d8[rr]*(mrgc+m0[rr]));
      xwa[i]=__float2bfloat16(x8[rr] + d8[rr]*(mwac+m1[rr]));
      xk[i] =__float2bfloat16(x8[rr] + d8[rr]*(mkc+m2[rr]));
      xv[i] =__float2bfloat16(x8[rr] + d8[rr]*(mvc+m3[rr]));
    }
  }
}

// ---------------- K5: fused second-stage, 8 rows per block; ACTs applied on load ----------------
__global__ __launch_bounds__(256) void k5_fuse(
    const float* __restrict__ hwa, const float* __restrict__ hk, const float* __restrict__ hv,
    const float* __restrict__ hrg,
    const float* __restrict__ dw2, const float* __restrict__ aaa_w2, const float* __restrict__ kkk_w2,
    const float* __restrict__ gate_w2, const float* __restrict__ ma_w2, const float* __restrict__ mk_w2,
    const float* __restrict__ mv_w2,
    const float* __restrict__ time_decay, const float* __restrict__ time_aaaaa,
    const float* __restrict__ misc_a, const float* __restrict__ misc_k, const float* __restrict__ misc_v,
    const float* __restrict__ v1,
    float* __restrict__ kbuf, float* __restrict__ vbuf, float* __restrict__ wexp,
    float* __restrict__ g, float* __restrict__ akv, float* __restrict__ bkv) {
  const int row0 = blockIdx.x*8, tid = threadIdx.x;
  __shared__ float s1[8][64], s2[8][24], s3[8][24], s4[8][120], s5[8][24], s6[8][24], s7[8][24];
  __shared__ float kkp[8][Cdim];
  __shared__ float aar[8][Cdim];
  __shared__ float hv_[8][Hdim];
  for (int idx=tid; idx<8*64; idx+=256){ int rr=idx>>6, q=idx&63; s1[rr][q]=tanhf(hwa[(size_t)(row0+rr)*112+q]); }
  for (int idx=tid; idx<8*24; idx+=256){
    int rr=idx/24, q=idx-rr*24;
    s2[rr][q]=hwa[(size_t)(row0+rr)*112+64+q];
    s5[rr][q]=hwa[(size_t)(row0+rr)*112+88+q];
    s3[rr][q]=tanhf(hk[(size_t)(row0+rr)*48+q]);
    s6[rr][q]=hk[(size_t)(row0+rr)*48+24+q];
    s7[rr][q]=hv[(size_t)(row0+rr)*24+q];
  }
  for (int idx=tid; idx<8*120; idx+=256){ int rr=idx/120, q=idx-rr*120; s4[rr][q]=sigm(hrg[(size_t)(row0+rr)*120+q]); }
  __syncthreads();
  for (int c=tid;c<Cdim;c+=256){
    float kraw[8], w8[8], a8[8];
    #pragma unroll
    for (int rr=0;rr<8;rr++) kraw[rr]=kbuf[(size_t)(row0+rr)*Cdim+c];
    {
      float zd[8];
      float tdc = time_decay[c];
      #pragma unroll
      for (int rr=0;rr<8;rr++) zd[rr]=tdc;
      #pragma unroll 8
      for (int q=0;q<64;q++){
        float wv=dw2[(size_t)q*Cdim+c];
        #pragma unroll
        for (int rr=0;rr<8;rr++) zd[rr]+=s1[rr][q]*wv;
      }
      #pragma unroll
      for (int rr=0;rr<8;rr++){
        float w = -softplusf(-zd[rr]) - 0.5f;
        w8[rr]=w;
        wexp[(size_t)(row0+rr)*Cdim+c]=expf(-expf(w));
      }
    }
    {
      float za[8], zk[8];
      float aac = time_aaaaa[c];
      #pragma unroll
      for (int rr=0;rr<8;rr++){ za[rr]=aac; zk[rr]=0.f; }
      #pragma unroll 8
      for (int q=0;q<24;q++){
        float wa=aaa_w2[(size_t)q*Cdim+c], wk=kkk_w2[(size_t)q*Cdim+c];
        #pragma unroll
        for (int rr=0;rr<8;rr++){ za[rr]+=s2[rr][q]*wa; zk[rr]+=s3[rr][q]*wk; }
      }
      #pragma unroll
      for (int rr=0;rr<8;rr++){
        a8[rr]=sigm(za[rr]);
        aar[rr][c]=a8[rr];
        kkp[rr][c]=kraw[rr]+zk[rr];
      }
    }
    {
      float zg[8]={};
      #pragma unroll 8
      for (int q=0;q<120;q++){
        float wv=gate_w2[(size_t)q*Cdim+c];
        #pragma unroll
        for (int rr=0;rr<8;rr++) zg[rr]+=s4[rr][q]*wv;
      }
      #pragma unroll
      for (int rr=0;rr<8;rr++) g[(size_t)(row0+rr)*Cdim+c]=zg[rr];
    }
    {
      float zma[8], zmk[8], zmv[8];
      float mac=misc_a[c], mkc=misc_k[c], mvc=misc_v[c];
      #pragma unroll
      for (int rr=0;rr<8;rr++){ zma[rr]=mac; zmk[rr]=mkc; zmv[rr]=mvc; }
      #pragma unroll 8
      for (int q=0;q<24;q++){
        float w5=ma_w2[(size_t)q*Cdim+c], w6=mk_w2[(size_t)q*Cdim+c], w7=mv_w2[(size_t)q*Cdim+c];
        #pragma unroll
        for (int rr=0;rr<8;rr++){ zma[rr]+=s5[rr][q]*w5; zmk[rr]+=s6[rr][q]*w6; zmv[rr]+=s7[rr][q]*w7; }
      }
      #pragma unroll
      for (int rr=0;rr<8;rr++){
        size_t i=(size_t)(row0+rr)*Cdim+c;
        float ma=sigm(zma[rr]), mk=sigm(zmk[rr]), mv=sigm(zmv[rr]);
        float v0=vbuf[i];
        vbuf[i]=v0+(v1[i]-v0)*mv;
        float k1=kraw[rr]*(ma + a8[rr]*(1.f-ma));
        kbuf[i]=k1*expf(fminf(w8[rr]*mk,0.f));
      }
    }
  }
  __syncthreads();
  for (int idx=tid; idx<8*Hdim; idx+=256){
    int rr=idx/Hdim, hh=idx-rr*Hdim;
    float s=0.f;
    #pragma unroll
    for (int j=0;j<Ndim;j++){ float q=kkp[rr][hh*Ndim+j]; s+=q*q; }
    hv_[rr][hh]=1.f/fmaxf(sqrtf(s),1e-12f);
  }
  __syncthreads();
  for (int c=tid;c<Cdim;c+=256){
    #pragma unroll
    for (int rr=0;rr<8;rr++){
      size_t i=(size_t)(row0+rr)*Cdim+c;
      float kkn=kkp[rr][c]*hv_[rr][c>>5];
      akv[i]=-kkn;
      bkv[i]=kkn*aar[rr][c];
    }
  }
}

// ---------------- K6 v4: 1 head / 64-thread block; lane owns rows {i0,i0+16} x 8 cols ----------------
// Single wave: no barriers. GLDS staging double-buffered; s_waitcnt vmcnt(0) per chunk.
// Quad reductions via DPP quad_perm (VALU pipe, not LDS).
__global__ __launch_bounds__(64) void k6_wkv(const float* __restrict__ r, const float* __restrict__ wd,
    const float* __restrict__ k, const float* __restrict__ v,
    const float* __restrict__ a, const float* __restrict__ b2, float* __restrict__ y) {
  const int lane = threadIdx.x;
  const int head = blockIdx.x;
  const int bb = head / Hdim, hh = head - bb*Hdim;
  const int i0 = lane >> 2;          // rows i0 and i0+16
  const int jq = lane & 3;           // 8-col group
  const int col = jq*8;
  __shared__ __align__(16) float sb[2][6][CH6][Ndim];   // 24 KB
  const float* gptr[6] = {r, wd, k, v, a, b2};
  const size_t gbase = (size_t)bb*Tdim*Cdim + (size_t)hh*Ndim;
  float S0[8], S1[8];
  #pragma unroll
  for (int m=0;m<8;m++){ S0[m]=0.f; S1[m]=0.f; }
  const int tl = lane>>3, c4 = (lane&7)*4;   // staging map: lane -> (t offset, col)

  auto STAGE = [&](int c, int buf){
    const size_t tb = (size_t)c*CH6;
    #pragma unroll
    for (int arr=0; arr<6; arr++){
      const float* gp = gptr[arr] + gbase;
      GLDS16(gp + (tb + tl)*Cdim + c4,     &sb[buf][arr][0][0]);
      GLDS16(gp + (tb + 8 + tl)*Cdim + c4, &sb[buf][arr][8][0]);
    }
  };

  STAGE(0, 0);
  asm volatile("s_waitcnt vmcnt(0)" ::: "memory");
  int cur = 0;
  const int NCH = Tdim/CH6;
  for (int c=0; c<NCH; ++c){
    if (c+1 < NCH) STAGE(c+1, cur^1);        // issue early; latency hides under 16 steps
    const size_t yb = gbase + (size_t)c*CH6*Cdim;
    #pragma unroll
    for (int t=0; t<CH6; t++){
      float av[8], wv[8], kv[8], bv[8], rv[8];
      *(float4*)&av[0]=*(const float4*)&sb[cur][4][t][col]; *(float4*)&av[4]=*(const float4*)&sb[cur][4][t][col+4];
      *(float4*)&wv[0]=*(const float4*)&sb[cur][1][t][col]; *(float4*)&wv[4]=*(const float4*)&sb[cur][1][t][col+4];
      *(float4*)&kv[0]=*(const float4*)&sb[cur][2][t][col]; *(float4*)&kv[4]=*(const float4*)&sb[cur][2][t][col+4];
      *(float4*)&bv[0]=*(const float4*)&sb[cur][5][t][col]; *(float4*)&bv[4]=*(const float4*)&sb[cur][5][t][col+4];
      *(float4*)&rv[0]=*(const float4*)&sb[cur][0][t][col]; *(float4*)&rv[4]=*(const float4*)&sb[cur][0][t][col+4];
      const float vl0 = sb[cur][3][t][i0];
      const float vl1 = sb[cur][3][t][i0+16];
      float sa0=0.f, sa1=0.f;
      #pragma unroll
      for (int j=0;j<8;j++){ sa0 += S0[j]*av[j]; sa1 += S1[j]*av[j]; }
      sa0 = dpp_add<0xB1>(sa0); sa0 = dpp_add<0x4E>(sa0);
      sa1 = dpp_add<0xB1>(sa1); sa1 = dpp_add<0x4E>(sa1);
      float y0=0.f, y1=0.f;
      #pragma unroll
      for (int j=0;j<8;j++){
        S0[j] = S0[j]*wv[j] + (sa0*bv[j] + vl0*kv[j]);
        S1[j] = S1[j]*wv[j] + (sa1*bv[j] + vl1*kv[j]);
        y0 += S0[j]*rv[j];
        y1 += S1[j]*rv[j];
      }
      y0 = dpp_add<0xB1>(y0); y0 = dpp_add<0x4E>(y0);
      y1 = dpp_add<0xB1>(y1); y1 = dpp_add<0x4E>(y1);
      if (jq == 0){
        y[yb + (size_t)t*Cdim + i0]      = y0;
        y[yb + (size_t)t*Cdim + i0 + 16] = y1;
      }
    }
    asm volatile("s_waitcnt vmcnt(0)" ::: "memory");
    cur ^= 1;
  }
}

// ---------------- K7: GroupNorm + bonus + gate -> bf16 ----------------
__global__ __launch_bounds__(256) void k7_post(const float* __restrict__ y,
    const float* __restrict__ r, const float* __restrict__ kf, const float* __restrict__ v,
    const float* __restrict__ g, const float* __restrict__ faaaa,
    const float* __restrict__ lnw, const float* __restrict__ lnb,
    __hip_bfloat16* __restrict__ ygate) {
  const int row = blockIdx.x, tid = threadIdx.x;
  __shared__ float sy[Cdim], srk[Cdim];
  __shared__ float smu[Hdim], srs[Hdim], sbon[Hdim];
  for (int c=tid;c<Cdim;c+=256){
    size_t i=(size_t)row*Cdim+c;
    float yv=y[i]; sy[c]=yv;
    srk[c]=r[i]*kf[i]*faaaa[c];
  }
  __syncthreads();
  if (tid<Hdim){
    float s=0.f,ss=0.f,bn=0.f;
    #pragma unroll
    for (int j=0;j<Ndim;j++){
      float q=sy[tid*Ndim+j]; s+=q; ss+=q*q; bn+=srk[tid*Ndim+j];
    }
    float mu=s*(1.f/Ndim);
    float var=ss*(1.f/Ndim)-mu*mu;
    smu[tid]=mu; srs[tid]=rsqrtf(var+6.4e-5f); sbon[tid]=bn;
  }
  __syncthreads();
  for (int c=tid;c<Cdim;c+=256){
    size_t i=(size_t)row*Cdim+c; int h=c>>5;
    float yn=(sy[c]-smu[h])*srs[h]*lnw[c]+lnb[c];
    ygate[i]=__float2bfloat16((yn+sbon[h]*v[i])*g[i]);
  }
}

// ---------------- K9: v1 passthrough ----------------
__global__ void k9_copy(const float* __restrict__ src, float* __restrict__ dst){
  int idx = blockIdx.x*256 + threadIdx.x;
  if (idx < BTdim*Cdim) dst[idx]=src[idx];
}

extern "C" void kernel_launch(void* const* d_in, const int* in_sizes, int n_in,
                              void* d_out, int out_size, void* d_ws, size_t ws_size,
                              hipStream_t stream) {
  const float* x      = (const float*)d_in[0];
  const float* v1     = (const float*)d_in[1];
  const float* maa_x  = (const float*)d_in[2];
  const float* maa_rg = (const float*)d_in[3];
  const float* maa_wa = (const float*)d_in[4];
  const float* maa_k  = (const float*)d_in[5];
  const float* maa_v  = (const float*)d_in[6];
  const float* time_decay = (const float*)d_in[7];
  const float* faaaa  = (const float*)d_in[8];
  const float* aaaaa  = (const float*)d_in[9];
  const float* maa_w1 = (const float*)d_in[10];
  const float* maa_w2 = (const float*)d_in[11];
  const float* dw1    = (const float*)d_in[12];
  const float* dw2    = (const float*)d_in[13];
  const float* aaa_w1 = (const float*)d_in[14];
  const float* aaa_w2 = (const float*)d_in[15];
  const float* kkk_w1 = (const float*)d_in[16];
  const float* kkk_w2 = (const float*)d_in[17];
  const float* gate_w1= (const float*)d_in[18];
  const float* gate_w2= (const float*)d_in[19];
  const float* ma_w1  = (const float*)d_in[20];
  const float* ma_w2  = (const float*)d_in[21];
  const float* misc_a = (const float*)d_in[22];
  const float* mk_w1  = (const float*)d_in[23];
  const float* mk_w2  = (const float*)d_in[24];
  const float* misc_k = (const float*)d_in[25];
  const float* mv_w1  = (const float*)d_in[26];
  const float* mv_w2  = (const float*)d_in[27];
  const float* misc_v = (const float*)d_in[28];
  const float* Wr     = (const float*)d_in[29];
  const float* Wk     = (const float*)d_in[30];
  const float* Wv     = (const float*)d_in[31];
  const float* Wo     = (const float*)d_in[32];
  const float* lnw    = (const float*)d_in[33];
  const float* lnb    = (const float*)d_in[34];
  float* out = (float*)d_out;

  float* ws = (float*)d_ws;
  const size_t BTC = (size_t)BTdim*Cdim;
  float* ws0 = ws + 0*BTC;   // xx -> ybuf
  float* ws1 = ws + 1*BTC;   // xxx_bf -> {xrg_bf,xwa_bf} -> akv -> yg_bf
  float* ws2 = ws + 2*BTC;   // {xk_bf,xv_bf} -> bkv
  float* rb  = ws + 3*BTC;
  float* kb  = ws + 4*BTC;
  float* vb  = ws + 5*BTC;
  float* wexp= ws + 6*BTC;
  float* gb  = ws + 7*BTC;
  float* p   = ws + 8*BTC;
  float* tm  = p;               p += (size_t)BTdim*112;
  float* hwa = p;               p += (size_t)BTdim*112;
  float* hk  = p;               p += (size_t)BTdim*48;
  float* hv  = p;               p += (size_t)BTdim*24;
  float* hrg = p;               p += (size_t)BTdim*120;
  __hip_bfloat16* WtR = (__hip_bfloat16*)p;   // 4 x 589824 bf16
  __hip_bfloat16* WtK = WtR + 589824;
  __hip_bfloat16* WtV = WtK + 589824;
  __hip_bfloat16* WtO = WtV + 589824;
  __hip_bfloat16* PWwa = WtO + 589824;        // 5 x 98304 bf16
  __hip_bfloat16* PWk  = PWwa + 98304;
  __hip_bfloat16* PWv  = PWk  + 98304;
  __hip_bfloat16* PWrg = PWv  + 98304;
  __hip_bfloat16* PWmaa= PWrg + 98304;

  float* xx  = ws0;
  __hip_bfloat16* xxx_bf = (__hip_bfloat16*)ws1;
  __hip_bfloat16* xrg_bf = (__hip_bfloat16*)ws1;
  __hip_bfloat16* xwa_bf = xrg_bf + BTC;
  __hip_bfloat16* xk_bf  = (__hip_bfloat16*)ws2;
  __hip_bfloat16* xv_bf  = xk_bf + BTC;
  float* akv = ws1;
  float* bkv = ws2;
  float* ybuf = ws0;
  __hip_bfloat16* yg_bf = (__hip_bfloat16*)ws1;

  dim3 blk(256);
  kconvW<<<dim3(24,24,4), blk, 0, stream>>>(Wr,Wk,Wv,Wo, WtR,WtK,WtV,WtO);
  kprep<<<dim3((5*128*768+255)/256), blk, 0, stream>>>(dw1,aaa_w1,ma_w1,kkk_w1,mk_w1,mv_w1,gate_w1,maa_w1,
                                                       PWwa,PWk,PWv,PWrg,PWmaa);
  k1_shift<<<dim3((BTdim*Cdim+255)/256), blk, 0, stream>>>(x, maa_x, xx, xxx_bf);
  gemm_mfma<<<dim3(1,64), blk, 0, stream>>>(xxx_bf, PWmaa, tm, BTdim, 112, Cdim);
  k2_mix<<<dim3(BTdim/8), blk, 0, stream>>>(x, xx, tm, maa_w2, maa_rg, maa_wa, maa_k, maa_v,
                                            xrg_bf, xwa_bf, xk_bf, xv_bf);
  gemm_mfma<<<dim3(6,64), blk, 0, stream>>>(xrg_bf, WtR, rb, BTdim, Cdim, Cdim);
  gemm_mfma<<<dim3(6,64), blk, 0, stream>>>(xk_bf,  WtK, kb, BTdim, Cdim, Cdim);
  gemm_mfma<<<dim3(6,64), blk, 0, stream>>>(xv_bf,  WtV, vb, BTdim, Cdim, Cdim);
  gemm_mfma<<<dim3(1,64), blk, 0, stream>>>(xwa_bf, PWwa, hwa, BTdim, 112, Cdim);
  gemm_mfma<<<dim3(1,64), blk, 0, stream>>>(xk_bf,  PWk,  hk,  BTdim, 48,  Cdim);
  gemm_mfma<<<dim3(1,64), blk, 0, stream>>>(xv_bf,  PWv,  hv,  BTdim, 24,  Cdim);
  gemm_mfma<<<dim3(1,64), blk, 0, stream>>>(xrg_bf, PWrg, hrg, BTdim, 120, Cdim);
  k5_fuse<<<dim3(BTdim/8), blk, 0, stream>>>(hwa,hk,hv,hrg,
      dw2,aaa_w2,kkk_w2,gate_w2,ma_w2,mk_w2,mv_w2,
      time_decay, aaaaa, misc_a, misc_k, misc_v, v1,
      kb, vb, wexp, gb, akv, bkv);
  k6_wkv<<<dim3(Bdim*Hdim), dim3(64), 0, stream>>>(rb, wexp, kb, vb, akv, bkv, ybuf);
  k7_post<<<dim3(BTdim), blk, 0, stream>>>(ybuf, rb, kb, vb, gb, faaaa, lnw, lnb, yg_bf);
  gemm_mfma<<<dim3(6,64), blk, 0, stream>>>(yg_bf, WtO, out, BTdim, Cdim, Cdim);
  k9_copy<<<dim3((BTdim*Cdim+255)/256), blk, 0, stream>>>(v1, out + BTC);
}